// Round 2
// baseline (814.790 us; speedup 1.0000x reference)
//
#include <hip/hip_runtime.h>

#define NN 100000
#define NE 600000

static __device__ __forceinline__ float bf2f(unsigned int u16) {
  union { unsigned int i; float f; } v;
  v.i = u16 << 16;
  return v.f;
}
static __device__ __forceinline__ unsigned short f2bf(float f) {
  union { float f; unsigned int i; } v;
  v.f = f;
  unsigned int x = v.i;
  x += 0x7FFFu + ((x >> 16) & 1u);  // round-to-nearest-even
  return (unsigned short)(x >> 16);
}

// ---------- CSR build ----------
__global__ void k_count(const int* __restrict__ dst, int* __restrict__ cnt, int E) {
  int i = blockIdx.x * blockDim.x + threadIdx.x;
  if (i < E) atomicAdd(&cnt[dst[i]], 1);
}

// single-block exclusive scan over n ints (in place), also copies to cur, writes off[n]=total
__global__ __launch_bounds__(1024) void k_scan(int* __restrict__ off, int* __restrict__ cur, int n) {
  __shared__ int wsum[16];
  __shared__ int carry_s, tile_tot;
  const int tid = threadIdx.x, wid = tid >> 6, lane = tid & 63;
  if (tid == 0) carry_s = 0;
  __syncthreads();
  for (int base = 0; base < n; base += 4096) {
    int i = base + tid * 4;
    int v0 = (i + 0 < n) ? off[i + 0] : 0;
    int v1 = (i + 1 < n) ? off[i + 1] : 0;
    int v2 = (i + 2 < n) ? off[i + 2] : 0;
    int v3 = (i + 3 < n) ? off[i + 3] : 0;
    int s = v0 + v1 + v2 + v3;
    int incl = s;
    #pragma unroll
    for (int d = 1; d < 64; d <<= 1) {
      int t = __shfl_up(incl, (unsigned)d);
      if (lane >= d) incl += t;
    }
    if (lane == 63) wsum[wid] = incl;
    __syncthreads();
    if (tid == 0) {
      int c = 0;
      for (int w = 0; w < 16; w++) { int t = wsum[w]; wsum[w] = c; c += t; }
      tile_tot = c;
    }
    __syncthreads();
    int excl = carry_s + wsum[wid] + (incl - s);
    if (i + 0 < n) { off[i + 0] = excl; cur[i + 0] = excl; } excl += v0;
    if (i + 1 < n) { off[i + 1] = excl; cur[i + 1] = excl; } excl += v1;
    if (i + 2 < n) { off[i + 2] = excl; cur[i + 2] = excl; } excl += v2;
    if (i + 3 < n) { off[i + 3] = excl; cur[i + 3] = excl; } excl += v3;
    __syncthreads();
    if (tid == 0) carry_s += tile_tot;
    __syncthreads();
  }
  if (tid == 0) off[n] = carry_s;
}

__global__ void k_fill(const int* __restrict__ src, const int* __restrict__ dst,
                       int* __restrict__ cur, int* __restrict__ esrc, int E) {
  int i = blockIdx.x * blockDim.x + threadIdx.x;
  if (i < E) {
    int p = atomicAdd(&cur[dst[i]], 1);
    esrc[p] = src[i];
  }
}

// ---------- fp32 -> bf16 cast (vectorized x4) ----------
__global__ void k_cast(const float* __restrict__ in, unsigned short* __restrict__ out, int n4) {
  int i = blockIdx.x * blockDim.x + threadIdx.x;
  if (i < n4) {
    float4 f = ((const float4*)in)[i];
    ushort4 o;
    o.x = f2bf(f.x); o.y = f2bf(f.y); o.z = f2bf(f.z); o.w = f2bf(f.w);
    ((ushort4*)out)[i] = o;
  }
}

// ---------- CSR gather-mean: one wave per node ----------
template <int C>
__global__ __launch_bounds__(64) void k_gather(const unsigned short* __restrict__ feat,
                                               const int* __restrict__ off,
                                               const int* __restrict__ esrc,
                                               unsigned short* __restrict__ mean) {
  const int v = blockIdx.x;
  const int lane = threadIdx.x;
  const int s0 = off[v], s1 = off[v + 1];
  if constexpr (C == 128) {
    float a0 = 0.f, a1 = 0.f;
    for (int e = s0; e < s1; e++) {
      int s = esrc[e];
      unsigned int u = ((const unsigned int*)(feat + (size_t)s * C))[lane];
      a0 += bf2f(u & 0xffffu);
      a1 += bf2f(u >> 16);
    }
    int d = s1 - s0;
    float inv = 1.0f / (float)(d > 1 ? d : 1);
    unsigned int o = (unsigned int)f2bf(a0 * inv) | ((unsigned int)f2bf(a1 * inv) << 16);
    ((unsigned int*)(mean + (size_t)v * C))[lane] = o;
  } else {
    float a0 = 0.f, a1 = 0.f, a2 = 0.f, a3 = 0.f;
    for (int e = s0; e < s1; e++) {
      int s = esrc[e];
      uint2 u = ((const uint2*)(feat + (size_t)s * C))[lane];
      a0 += bf2f(u.x & 0xffffu); a1 += bf2f(u.x >> 16);
      a2 += bf2f(u.y & 0xffffu); a3 += bf2f(u.y >> 16);
    }
    int d = s1 - s0;
    float inv = 1.0f / (float)(d > 1 ? d : 1);
    uint2 o;
    o.x = (unsigned int)f2bf(a0 * inv) | ((unsigned int)f2bf(a1 * inv) << 16);
    o.y = (unsigned int)f2bf(a2 * inv) | ((unsigned int)f2bf(a3 * inv) << 16);
    ((uint2*)(mean + (size_t)v * C))[lane] = o;
  }
}

// ---------- dual-A fp32 GEMM: out = A1@W1 + A2@W2 + b, optional relu ----------
// A: M x K bf16 (row-major), W: K x N fp32 (row-major). Tile 64x64, BK=32, 256 thr, 4x4 micro.
__global__ __launch_bounds__(256) void k_gemm(
    const unsigned short* __restrict__ A1, const float* __restrict__ W1,
    const unsigned short* __restrict__ A2, const float* __restrict__ W2,
    const float* __restrict__ bias, int M, int K, int N,
    unsigned short* __restrict__ outB, float* __restrict__ outF, int relu) {
  __shared__ float As[32][68];   // [k][m], pad for alignment
  __shared__ float Ws[32][64];   // [k][n]
  const int t = threadIdx.x;
  const int tm = t & 15, tn = t >> 4;
  const int m0 = blockIdx.x * 64, n0 = blockIdx.y * 64;
  const int lm = t >> 2;         // staging: row 0..63
  const int lk = (t & 3) * 8;    // staging: k offset 0,8,16,24

  float acc[4][4];
  #pragma unroll
  for (int i = 0; i < 4; i++)
    #pragma unroll
    for (int j = 0; j < 4; j++) acc[i][j] = 0.f;

  #pragma unroll
  for (int ph = 0; ph < 2; ph++) {
    const unsigned short* A = ph ? A2 : A1;
    const float* W = ph ? W2 : W1;
    for (int k0 = 0; k0 < K; k0 += 32) {
      uint4 u = make_uint4(0u, 0u, 0u, 0u);
      if (m0 + lm < M)
        u = *(const uint4*)(A + (size_t)(m0 + lm) * K + k0 + lk);
      float4 w0 = *(const float4*)(W + (size_t)(k0 + tn) * N + n0 + tm * 4);
      float4 w1 = *(const float4*)(W + (size_t)(k0 + 16 + tn) * N + n0 + tm * 4);
      __syncthreads();  // protect previous tile's LDS reads
      As[lk + 0][lm] = bf2f(u.x & 0xffffu);
      As[lk + 1][lm] = bf2f(u.x >> 16);
      As[lk + 2][lm] = bf2f(u.y & 0xffffu);
      As[lk + 3][lm] = bf2f(u.y >> 16);
      As[lk + 4][lm] = bf2f(u.z & 0xffffu);
      As[lk + 5][lm] = bf2f(u.z >> 16);
      As[lk + 6][lm] = bf2f(u.w & 0xffffu);
      As[lk + 7][lm] = bf2f(u.w >> 16);
      *(float4*)&Ws[tn][tm * 4] = w0;
      *(float4*)&Ws[tn + 16][tm * 4] = w1;
      __syncthreads();
      #pragma unroll
      for (int k = 0; k < 32; k++) {
        float4 a = *(const float4*)&As[k][tm * 4];
        float4 w = *(const float4*)&Ws[k][tn * 4];
        acc[0][0] += a.x * w.x; acc[0][1] += a.x * w.y; acc[0][2] += a.x * w.z; acc[0][3] += a.x * w.w;
        acc[1][0] += a.y * w.x; acc[1][1] += a.y * w.y; acc[1][2] += a.y * w.z; acc[1][3] += a.y * w.w;
        acc[2][0] += a.z * w.x; acc[2][1] += a.z * w.y; acc[2][2] += a.z * w.z; acc[2][3] += a.z * w.w;
        acc[3][0] += a.w * w.x; acc[3][1] += a.w * w.y; acc[3][2] += a.w * w.z; acc[3][3] += a.w * w.w;
      }
    }
  }

  #pragma unroll
  for (int i = 0; i < 4; i++) {
    int m = m0 + tm * 4 + i;
    if (m < M) {
      #pragma unroll
      for (int j = 0; j < 4; j++) {
        int n = n0 + tn * 4 + j;
        float v = acc[i][j] + bias[n];
        if (relu) v = fmaxf(v, 0.f);
        if (outB) outB[(size_t)m * N + n] = f2bf(v);
        else      outF[(size_t)m * N + n] = v;
      }
    }
  }
}

// ---------- log_softmax over 64 cols, one wave per row ----------
__global__ __launch_bounds__(256) void k_lsm(float* __restrict__ out) {
  int row = blockIdx.x * 4 + (threadIdx.x >> 6);
  int lane = threadIdx.x & 63;
  float v = out[(size_t)row * 64 + lane];
  float m = v;
  #pragma unroll
  for (int s = 32; s; s >>= 1) m = fmaxf(m, __shfl_xor(m, s));
  float e = expf(v - m);
  float sum = e;
  #pragma unroll
  for (int s = 32; s; s >>= 1) sum += __shfl_xor(sum, s);
  out[(size_t)row * 64 + lane] = v - m - logf(sum);
}

extern "C" void kernel_launch(void* const* d_in, const int* in_sizes, int n_in,
                              void* d_out, int out_size, void* d_ws, size_t ws_size,
                              hipStream_t stream) {
  const float* x   = (const float*)d_in[0];
  const int*   ei  = (const int*)d_in[1];
  const float* W1l = (const float*)d_in[2];
  const float* W1r = (const float*)d_in[3];
  const float* b1  = (const float*)d_in[4];
  const float* W2l = (const float*)d_in[5];
  const float* W2r = (const float*)d_in[6];
  const float* b2  = (const float*)d_in[7];
  const float* W3l = (const float*)d_in[8];
  const float* W3r = (const float*)d_in[9];
  const float* b3  = (const float*)d_in[10];
  float* out = (float*)d_out;
  const int* src = ei;
  const int* dst = ei + NE;

  char* w = (char*)d_ws;
  auto alloc = [&](size_t bytes) {
    char* p = w;
    w += (bytes + 255) & ~(size_t)255;
    return p;
  };
  int* off  = (int*)alloc((NN + 1) * sizeof(int));
  int* cur  = (int*)alloc(NN * sizeof(int));
  int* esrc = (int*)alloc((size_t)NE * sizeof(int));
  unsigned short* xb = (unsigned short*)alloc((size_t)NN * 128 * 2);
  unsigned short* mb = (unsigned short*)alloc((size_t)NN * 256 * 2);
  unsigned short* h1 = (unsigned short*)alloc((size_t)NN * 256 * 2);
  unsigned short* h2 = (unsigned short*)alloc((size_t)NN * 128 * 2);

  hipMemsetAsync(off, 0, (NN + 1) * sizeof(int), stream);
  k_count<<<(NE + 255) / 256, 256, 0, stream>>>(dst, off, NE);
  k_scan<<<1, 1024, 0, stream>>>(off, cur, NN);
  k_fill<<<(NE + 255) / 256, 256, 0, stream>>>(src, dst, cur, esrc, NE);
  k_cast<<<((NN * 128 / 4) + 255) / 256, 256, 0, stream>>>(x, xb, NN * 128 / 4);

  // layer 1: in=xb (C=128) -> h1 (C=256), relu
  k_gather<128><<<NN, 64, 0, stream>>>(xb, off, esrc, mb);
  k_gemm<<<dim3((NN + 63) / 64, 256 / 64), 256, 0, stream>>>(mb, W1l, xb, W1r, b1, NN, 128, 256, h1, nullptr, 1);
  // layer 2: in=h1 (C=256) -> h2 (C=128), relu
  k_gather<256><<<NN, 64, 0, stream>>>(h1, off, esrc, mb);
  k_gemm<<<dim3((NN + 63) / 64, 128 / 64), 256, 0, stream>>>(mb, W2l, h1, W2r, b2, NN, 256, 128, h2, nullptr, 1);
  // layer 3: in=h2 (C=128) -> out (C=64), no relu
  k_gather<128><<<NN, 64, 0, stream>>>(h2, off, esrc, mb);
  k_gemm<<<dim3((NN + 63) / 64, 64 / 64), 256, 0, stream>>>(mb, W3l, h2, W3r, b3, NN, 128, 64, nullptr, out, 0);
  // log_softmax in place
  k_lsm<<<NN / 4, 256, 0, stream>>>(out);
}

// Round 3
// 549.321 us; speedup vs baseline: 1.4833x; 1.4833x over previous
//
#include <hip/hip_runtime.h>

#define NN 100000
#define NE 600000

typedef __attribute__((ext_vector_type(8))) short short8;   // 8 bf16 (4 VGPRs)
typedef __attribute__((ext_vector_type(4))) float f32x4;    // MFMA C/D frag

static __device__ __forceinline__ float bf2f(unsigned int u16) {
  union { unsigned int i; float f; } v;
  v.i = u16 << 16;
  return v.f;
}
static __device__ __forceinline__ unsigned short f2bf(float f) {
  union { float f; unsigned int i; } v;
  v.f = f;
  unsigned int x = v.i;
  x += 0x7FFFu + ((x >> 16) & 1u);  // round-to-nearest-even
  return (unsigned short)(x >> 16);
}

static __device__ __forceinline__ void async_cp16(const unsigned short* g, unsigned short* l) {
  __builtin_amdgcn_global_load_lds(
      (const __attribute__((address_space(1))) unsigned int*)g,
      (__attribute__((address_space(3))) unsigned int*)l,
      16, 0, 0);
}

// ---------- CSR build ----------
__global__ void k_count(const int* __restrict__ dst, int* __restrict__ cnt, int E) {
  int i = blockIdx.x * blockDim.x + threadIdx.x;
  if (i < E) atomicAdd(&cnt[dst[i]], 1);
}

// single-block exclusive scan over n ints (in place), also copies to cur, writes off[n]=total
__global__ __launch_bounds__(1024) void k_scan(int* __restrict__ off, int* __restrict__ cur, int n) {
  __shared__ int wsum[16];
  __shared__ int carry_s, tile_tot;
  const int tid = threadIdx.x, wid = tid >> 6, lane = tid & 63;
  if (tid == 0) carry_s = 0;
  __syncthreads();
  for (int base = 0; base < n; base += 4096) {
    int i = base + tid * 4;
    int v0 = (i + 0 < n) ? off[i + 0] : 0;
    int v1 = (i + 1 < n) ? off[i + 1] : 0;
    int v2 = (i + 2 < n) ? off[i + 2] : 0;
    int v3 = (i + 3 < n) ? off[i + 3] : 0;
    int s = v0 + v1 + v2 + v3;
    int incl = s;
    #pragma unroll
    for (int d = 1; d < 64; d <<= 1) {
      int t = __shfl_up(incl, (unsigned)d);
      if (lane >= d) incl += t;
    }
    if (lane == 63) wsum[wid] = incl;
    __syncthreads();
    if (tid == 0) {
      int c = 0;
      for (int w = 0; w < 16; w++) { int t = wsum[w]; wsum[w] = c; c += t; }
      tile_tot = c;
    }
    __syncthreads();
    int excl = carry_s + wsum[wid] + (incl - s);
    if (i + 0 < n) { off[i + 0] = excl; cur[i + 0] = excl; } excl += v0;
    if (i + 1 < n) { off[i + 1] = excl; cur[i + 1] = excl; } excl += v1;
    if (i + 2 < n) { off[i + 2] = excl; cur[i + 2] = excl; } excl += v2;
    if (i + 3 < n) { off[i + 3] = excl; cur[i + 3] = excl; } excl += v3;
    __syncthreads();
    if (tid == 0) carry_s += tile_tot;
    __syncthreads();
  }
  if (tid == 0) off[n] = carry_s;
}

__global__ void k_fill(const int* __restrict__ src, const int* __restrict__ dst,
                       int* __restrict__ cur, int* __restrict__ esrc, int E) {
  int i = blockIdx.x * blockDim.x + threadIdx.x;
  if (i < E) {
    int p = atomicAdd(&cur[dst[i]], 1);
    esrc[p] = src[i];
  }
}

// ---------- fp32 -> bf16 cast (vectorized x4) ----------
__global__ void k_cast(const float* __restrict__ in, unsigned short* __restrict__ out, int n4) {
  int i = blockIdx.x * blockDim.x + threadIdx.x;
  if (i < n4) {
    float4 f = ((const float4*)in)[i];
    ushort4 o;
    o.x = f2bf(f.x); o.y = f2bf(f.y); o.z = f2bf(f.z); o.w = f2bf(f.w);
    ((ushort4*)out)[i] = o;
  }
}

// ---------- weight transpose + cast: W[K][N] fp32 -> Wt[N][K] bf16 ----------
__global__ void k_wt(const float* __restrict__ W, unsigned short* __restrict__ Wt, int K, int N) {
  int i = blockIdx.x * blockDim.x + threadIdx.x;
  if (i < N * K) {
    int n = i / K, k = i - n * K;
    Wt[i] = f2bf(W[(size_t)k * N + n]);
  }
}

// ---------- CSR gather-mean: one wave per node ----------
template <int C>
__global__ __launch_bounds__(64) void k_gather(const unsigned short* __restrict__ feat,
                                               const int* __restrict__ off,
                                               const int* __restrict__ esrc,
                                               unsigned short* __restrict__ mean) {
  const int v = blockIdx.x;
  const int lane = threadIdx.x;
  const int s0 = off[v], s1 = off[v + 1];
  if constexpr (C == 128) {
    float a0 = 0.f, a1 = 0.f;
    for (int e = s0; e < s1; e++) {
      int s = esrc[e];
      unsigned int u = ((const unsigned int*)(feat + (size_t)s * C))[lane];
      a0 += bf2f(u & 0xffffu);
      a1 += bf2f(u >> 16);
    }
    int d = s1 - s0;
    float inv = 1.0f / (float)(d > 1 ? d : 1);
    unsigned int o = (unsigned int)f2bf(a0 * inv) | ((unsigned int)f2bf(a1 * inv) << 16);
    ((unsigned int*)(mean + (size_t)v * C))[lane] = o;
  } else {
    float a0 = 0.f, a1 = 0.f, a2 = 0.f, a3 = 0.f;
    for (int e = s0; e < s1; e++) {
      int s = esrc[e];
      uint2 u = ((const uint2*)(feat + (size_t)s * C))[lane];
      a0 += bf2f(u.x & 0xffffu); a1 += bf2f(u.x >> 16);
      a2 += bf2f(u.y & 0xffffu); a3 += bf2f(u.y >> 16);
    }
    int d = s1 - s0;
    float inv = 1.0f / (float)(d > 1 ? d : 1);
    uint2 o;
    o.x = (unsigned int)f2bf(a0 * inv) | ((unsigned int)f2bf(a1 * inv) << 16);
    o.y = (unsigned int)f2bf(a2 * inv) | ((unsigned int)f2bf(a3 * inv) << 16);
    ((uint2*)(mean + (size_t)v * C))[lane] = o;
  }
}

// ---------- dual-A bf16 MFMA GEMM: out = A1@W1 + A2@W2 + b ----------
// A: M x K bf16 row-major. Wt: N x K bf16 (pre-transposed). Tile 128 x BN, BK=32.
// BN=128 -> 256 thr (4 waves, 2x2 wave grid); BN=64 -> 128 thr (2 waves stacked on m).
// m97 structure: global_load_lds width-16 staging, 16 mfma + 8 ds_read_b128 per wave per K-step.
template <int BN>
__global__ __launch_bounds__(BN * 2) void k_gmm(
    const unsigned short* __restrict__ A1, const unsigned short* __restrict__ Wt1,
    const unsigned short* __restrict__ A2, const unsigned short* __restrict__ Wt2,
    const float* __restrict__ bias, int M, int K, int N,
    unsigned short* __restrict__ outB, float* __restrict__ outF, int relu) {
  constexpr int NWAVE = BN / 32;     // 4 or 2
  constexpr int ACHUNKS = 8;         // A tile: 128 rows x 64 B = 8 KB = 8 x 1 KB chunks
  constexpr int BCHUNKS = BN / 16;   // B tile: BN rows x 64 B
  __shared__ unsigned short As[128 * 32];
  __shared__ unsigned short Bs[BN * 32];
  const int t = threadIdx.x;
  const int w = t >> 6, lane = t & 63;
  const int quad = lane >> 4, l15 = lane & 15;
  const int wm = w & 1, wn = w >> 1;  // BN=64: wn==0 always
  const int m0 = blockIdx.x * 128, n0 = blockIdx.y * BN;
  const int srow = lane >> 2, skc = (lane & 3) * 8;  // staging: row-in-chunk, k elem offset

  f32x4 acc[4][4];
  #pragma unroll
  for (int i = 0; i < 4; i++)
    #pragma unroll
    for (int j = 0; j < 4; j++) acc[i][j] = (f32x4){0.f, 0.f, 0.f, 0.f};

  #pragma unroll
  for (int ph = 0; ph < 2; ph++) {
    const unsigned short* A = ph ? A2 : A1;
    const unsigned short* Wt = ph ? Wt2 : Wt1;
    for (int k0 = 0; k0 < K; k0 += 32) {
      // stage A tile (rows m0..m0+127, k0..k0+31) -> As row-major [128][32]
      #pragma unroll
      for (int c = w; c < ACHUNKS; c += NWAVE) {
        int rg = m0 + c * 16 + srow;
        if (rg >= M) rg = M - 1;  // clamp; stores are predicated
        async_cp16(A + (size_t)rg * K + k0 + skc, As + c * 512);
      }
      // stage B tile (Wt rows n0..n0+BN-1, k0..k0+31) -> Bs row-major [BN][32]
      #pragma unroll
      for (int c = w; c < BCHUNKS; c += NWAVE) {
        async_cp16(Wt + (size_t)(n0 + c * 16 + srow) * K + k0 + skc, Bs + c * 512);
      }
      __syncthreads();  // drains vmcnt: staged data visible
      short8 af[4], bfr[4];
      #pragma unroll
      for (int mt = 0; mt < 4; mt++)
        af[mt] = *(const short8*)&As[(wm * 64 + mt * 16 + l15) * 32 + quad * 8];
      #pragma unroll
      for (int nt = 0; nt < 4; nt++)
        bfr[nt] = *(const short8*)&Bs[(wn * 64 + nt * 16 + l15) * 32 + quad * 8];
      #pragma unroll
      for (int mt = 0; mt < 4; mt++)
        #pragma unroll
        for (int nt = 0; nt < 4; nt++)
          acc[mt][nt] = __builtin_amdgcn_mfma_f32_16x16x32_bf16(af[mt], bfr[nt], acc[mt][nt], 0, 0, 0);
      __syncthreads();  // protect LDS before next staging round
    }
  }

  // epilogue: C/D layout col=lane&15, row=quad*4+reg (m89-verified)
  #pragma unroll
  for (int nt = 0; nt < 4; nt++) {
    int n = n0 + wn * 64 + nt * 16 + l15;
    float bia = bias[n];
    #pragma unroll
    for (int mt = 0; mt < 4; mt++) {
      #pragma unroll
      for (int r = 0; r < 4; r++) {
        int m = m0 + wm * 64 + mt * 16 + quad * 4 + r;
        if (m < M) {
          float v = acc[mt][nt][r] + bia;
          if (relu) v = fmaxf(v, 0.f);
          if (outB) outB[(size_t)m * N + n] = f2bf(v);
          else      outF[(size_t)m * N + n] = v;
        }
      }
    }
  }
}

// ---------- log_softmax over 64 cols, one wave per row ----------
__global__ __launch_bounds__(256) void k_lsm(float* __restrict__ out) {
  int row = blockIdx.x * 4 + (threadIdx.x >> 6);
  int lane = threadIdx.x & 63;
  float v = out[(size_t)row * 64 + lane];
  float m = v;
  #pragma unroll
  for (int s = 32; s; s >>= 1) m = fmaxf(m, __shfl_xor(m, s));
  float e = expf(v - m);
  float sum = e;
  #pragma unroll
  for (int s = 32; s; s >>= 1) sum += __shfl_xor(sum, s);
  out[(size_t)row * 64 + lane] = v - m - logf(sum);
}

extern "C" void kernel_launch(void* const* d_in, const int* in_sizes, int n_in,
                              void* d_out, int out_size, void* d_ws, size_t ws_size,
                              hipStream_t stream) {
  const float* x   = (const float*)d_in[0];
  const int*   ei  = (const int*)d_in[1];
  const float* W1l = (const float*)d_in[2];
  const float* W1r = (const float*)d_in[3];
  const float* b1  = (const float*)d_in[4];
  const float* W2l = (const float*)d_in[5];
  const float* W2r = (const float*)d_in[6];
  const float* b2  = (const float*)d_in[7];
  const float* W3l = (const float*)d_in[8];
  const float* W3r = (const float*)d_in[9];
  const float* b3  = (const float*)d_in[10];
  float* out = (float*)d_out;
  const int* src = ei;
  const int* dst = ei + NE;

  char* w = (char*)d_ws;
  auto alloc = [&](size_t bytes) {
    char* p = w;
    w += (bytes + 255) & ~(size_t)255;
    return p;
  };
  int* off  = (int*)alloc((NN + 1) * sizeof(int));
  int* cur  = (int*)alloc(NN * sizeof(int));
  int* esrc = (int*)alloc((size_t)NE * sizeof(int));
  unsigned short* xb = (unsigned short*)alloc((size_t)NN * 128 * 2);
  unsigned short* mb = (unsigned short*)alloc((size_t)NN * 256 * 2);
  unsigned short* h1 = (unsigned short*)alloc((size_t)NN * 256 * 2);
  unsigned short* h2 = (unsigned short*)alloc((size_t)NN * 128 * 2);
  unsigned short* t1l = (unsigned short*)alloc(128 * 256 * 2);
  unsigned short* t1r = (unsigned short*)alloc(128 * 256 * 2);
  unsigned short* t2l = (unsigned short*)alloc(256 * 128 * 2);
  unsigned short* t2r = (unsigned short*)alloc(256 * 128 * 2);
  unsigned short* t3l = (unsigned short*)alloc(128 * 64 * 2);
  unsigned short* t3r = (unsigned short*)alloc(128 * 64 * 2);

  hipMemsetAsync(off, 0, (NN + 1) * sizeof(int), stream);
  k_count<<<(NE + 255) / 256, 256, 0, stream>>>(dst, off, NE);
  k_scan<<<1, 1024, 0, stream>>>(off, cur, NN);
  k_fill<<<(NE + 255) / 256, 256, 0, stream>>>(src, dst, cur, esrc, NE);
  k_cast<<<((NN * 128 / 4) + 255) / 256, 256, 0, stream>>>(x, xb, NN * 128 / 4);
  // weight transposes (fp32 [K][N] -> bf16 [N][K])
  k_wt<<<(128 * 256 + 255) / 256, 256, 0, stream>>>(W1l, t1l, 128, 256);
  k_wt<<<(128 * 256 + 255) / 256, 256, 0, stream>>>(W1r, t1r, 128, 256);
  k_wt<<<(256 * 128 + 255) / 256, 256, 0, stream>>>(W2l, t2l, 256, 128);
  k_wt<<<(256 * 128 + 255) / 256, 256, 0, stream>>>(W2r, t2r, 256, 128);
  k_wt<<<(128 * 64 + 255) / 256, 256, 0, stream>>>(W3l, t3l, 128, 64);
  k_wt<<<(128 * 64 + 255) / 256, 256, 0, stream>>>(W3r, t3r, 128, 64);

  const int MB = (NN + 127) / 128;  // 782
  // layer 1: in=xb (C=128) -> h1 (C=256), relu
  k_gather<128><<<NN, 64, 0, stream>>>(xb, off, esrc, mb);
  k_gmm<128><<<dim3(MB, 2), 256, 0, stream>>>(mb, t1l, xb, t1r, b1, NN, 128, 256, h1, nullptr, 1);
  // layer 2: in=h1 (C=256) -> h2 (C=128), relu
  k_gather<256><<<NN, 64, 0, stream>>>(h1, off, esrc, mb);
  k_gmm<128><<<dim3(MB, 1), 256, 0, stream>>>(mb, t2l, h1, t2r, b2, NN, 256, 128, h2, nullptr, 1);
  // layer 3: in=h2 (C=128) -> out (C=64), no relu
  k_gather<128><<<NN, 64, 0, stream>>>(h2, off, esrc, mb);
  k_gmm<64><<<dim3(MB, 1), 128, 0, stream>>>(mb, t3l, h2, t3r, b3, NN, 128, 64, nullptr, out, 0);
  // log_softmax in place
  k_lsm<<<NN / 4, 256, 0, stream>>>(out);
}

// Round 4
// 459.236 us; speedup vs baseline: 1.7742x; 1.1962x over previous
//
#include <hip/hip_runtime.h>

#define NN 100000
#define NE 600000

typedef __attribute__((ext_vector_type(8))) short short8;   // 8 bf16 (4 VGPRs)
typedef __attribute__((ext_vector_type(4))) float f32x4;    // MFMA C/D frag

static __device__ __forceinline__ float bf2f(unsigned int u16) {
  union { unsigned int i; float f; } v;
  v.i = u16 << 16;
  return v.f;
}
static __device__ __forceinline__ unsigned short f2bf(float f) {
  union { float f; unsigned int i; } v;
  v.f = f;
  unsigned int x = v.i;
  x += 0x7FFFu + ((x >> 16) & 1u);  // round-to-nearest-even
  return (unsigned short)(x >> 16);
}

static __device__ __forceinline__ void async_cp16(const unsigned short* g, unsigned short* l) {
  __builtin_amdgcn_global_load_lds(
      (const __attribute__((address_space(1))) unsigned int*)g,
      (__attribute__((address_space(3))) unsigned int*)l,
      16, 0, 0);
}

// ---------- CSR build ----------
__global__ void k_count(const int* __restrict__ dst, int* __restrict__ cnt, int E) {
  int i = blockIdx.x * blockDim.x + threadIdx.x;
  if (i < E) atomicAdd(&cnt[dst[i]], 1);
}

// multi-block scan, stage 1: per-block (1024 elems) reduce -> part[b]
__global__ __launch_bounds__(256) void k_red(const int* __restrict__ off, int* __restrict__ part, int n) {
  __shared__ int ws[4];
  const int tid = threadIdx.x, wid = tid >> 6, lane = tid & 63;
  int i = blockIdx.x * 1024 + tid * 4;
  int s = 0;
  #pragma unroll
  for (int j = 0; j < 4; j++) if (i + j < n) s += off[i + j];
  #pragma unroll
  for (int d = 32; d; d >>= 1) s += __shfl_xor(s, d);
  if (lane == 0) ws[wid] = s;
  __syncthreads();
  if (tid == 0) part[blockIdx.x] = ws[0] + ws[1] + ws[2] + ws[3];
}

// stage 2: one block scans the (<=256) partials exclusively; writes off[n]=total
__global__ __launch_bounds__(256) void k_scan1(int* __restrict__ part, int nb, int* __restrict__ off, int n) {
  __shared__ int wsum[4];
  const int tid = threadIdx.x, wid = tid >> 6, lane = tid & 63;
  int v = (tid < nb) ? part[tid] : 0;
  int incl = v;
  #pragma unroll
  for (int d = 1; d < 64; d <<= 1) {
    int t = __shfl_up(incl, (unsigned)d);
    if (lane >= d) incl += t;
  }
  if (lane == 63) wsum[wid] = incl;
  __syncthreads();
  if (tid == 0) {
    int c = 0;
    #pragma unroll
    for (int w = 0; w < 4; w++) { int t = wsum[w]; wsum[w] = c; c += t; }
    off[n] = c;  // total edge count
  }
  __syncthreads();
  if (tid < nb) part[tid] = wsum[wid] + incl - v;
}

// stage 3: per-block local scan + part[b] offset; writes off (exclusive) and cur copy
__global__ __launch_bounds__(256) void k_add(int* __restrict__ off, int* __restrict__ cur,
                                             const int* __restrict__ part, int n) {
  __shared__ int wsum[4];
  const int tid = threadIdx.x, wid = tid >> 6, lane = tid & 63;
  int i = blockIdx.x * 1024 + tid * 4;
  int v0 = (i + 0 < n) ? off[i + 0] : 0;
  int v1 = (i + 1 < n) ? off[i + 1] : 0;
  int v2 = (i + 2 < n) ? off[i + 2] : 0;
  int v3 = (i + 3 < n) ? off[i + 3] : 0;
  int s = v0 + v1 + v2 + v3;
  int incl = s;
  #pragma unroll
  for (int d = 1; d < 64; d <<= 1) {
    int t = __shfl_up(incl, (unsigned)d);
    if (lane >= d) incl += t;
  }
  if (lane == 63) wsum[wid] = incl;
  __syncthreads();
  if (tid == 0) {
    int c = 0;
    #pragma unroll
    for (int w = 0; w < 4; w++) { int t = wsum[w]; wsum[w] = c; c += t; }
  }
  __syncthreads();
  int excl = part[blockIdx.x] + wsum[wid] + (incl - s);
  if (i + 0 < n) { off[i + 0] = excl; cur[i + 0] = excl; } excl += v0;
  if (i + 1 < n) { off[i + 1] = excl; cur[i + 1] = excl; } excl += v1;
  if (i + 2 < n) { off[i + 2] = excl; cur[i + 2] = excl; } excl += v2;
  if (i + 3 < n) { off[i + 3] = excl; cur[i + 3] = excl; } excl += v3;
}

__global__ void k_fill(const int* __restrict__ src, const int* __restrict__ dst,
                       int* __restrict__ cur, int* __restrict__ esrc, int E) {
  int i = blockIdx.x * blockDim.x + threadIdx.x;
  if (i < E) {
    int p = atomicAdd(&cur[dst[i]], 1);
    esrc[p] = src[i];
  }
}

// ---------- fp32 -> bf16 cast (vectorized x4) ----------
__global__ void k_cast(const float* __restrict__ in, unsigned short* __restrict__ out, int n4) {
  int i = blockIdx.x * blockDim.x + threadIdx.x;
  if (i < n4) {
    float4 f = ((const float4*)in)[i];
    ushort4 o;
    o.x = f2bf(f.x); o.y = f2bf(f.y); o.z = f2bf(f.z); o.w = f2bf(f.w);
    ((ushort4*)out)[i] = o;
  }
}

// ---------- weight transpose + cast: W[K][N] fp32 -> Wt[N][K] bf16 ----------
__global__ void k_wt(const float* __restrict__ W, unsigned short* __restrict__ Wt, int K, int N) {
  int i = blockIdx.x * blockDim.x + threadIdx.x;
  if (i < N * K) {
    int n = i / K, k = i - n * K;
    Wt[i] = f2bf(W[(size_t)k * N + n]);
  }
}

// ---------- CSR gather-mean: 4 waves/block, one node per wave ----------
// Edge indices pre-loaded one-per-lane + __shfl broadcast; row loads grouped x4 for MLP.
template <int C>
__global__ __launch_bounds__(256) void k_gather(const unsigned short* __restrict__ feat,
                                                const int* __restrict__ off,
                                                const int* __restrict__ esrc,
                                                unsigned short* __restrict__ mean) {
  const int v = blockIdx.x * 4 + (threadIdx.x >> 6);   // NN % 4 == 0
  const int lane = threadIdx.x & 63;
  const int s0 = off[v], deg = off[v + 1] - s0;

  if constexpr (C == 128) {
    const unsigned int* fp = (const unsigned int*)feat;  // 64 uints/row
    float a0 = 0.f, a1 = 0.f;
    if (deg <= 64) {
      int idx = (lane < deg) ? esrc[s0 + lane] : 0;
      int e = 0;
      for (; e + 4 <= deg; e += 4) {
        int i0 = __shfl(idx, e), i1 = __shfl(idx, e + 1), i2 = __shfl(idx, e + 2), i3 = __shfl(idx, e + 3);
        unsigned int u0 = fp[(size_t)i0 * 64 + lane];
        unsigned int u1 = fp[(size_t)i1 * 64 + lane];
        unsigned int u2 = fp[(size_t)i2 * 64 + lane];
        unsigned int u3 = fp[(size_t)i3 * 64 + lane];
        a0 += bf2f(u0 & 0xffffu); a1 += bf2f(u0 >> 16);
        a0 += bf2f(u1 & 0xffffu); a1 += bf2f(u1 >> 16);
        a0 += bf2f(u2 & 0xffffu); a1 += bf2f(u2 >> 16);
        a0 += bf2f(u3 & 0xffffu); a1 += bf2f(u3 >> 16);
      }
      for (; e < deg; e++) {
        int s = __shfl(idx, e);
        unsigned int u = fp[(size_t)s * 64 + lane];
        a0 += bf2f(u & 0xffffu); a1 += bf2f(u >> 16);
      }
    } else {
      for (int e = s0; e < s0 + deg; e++) {
        int s = esrc[e];
        unsigned int u = fp[(size_t)s * 64 + lane];
        a0 += bf2f(u & 0xffffu); a1 += bf2f(u >> 16);
      }
    }
    float inv = 1.0f / (float)(deg > 1 ? deg : 1);
    unsigned int o = (unsigned int)f2bf(a0 * inv) | ((unsigned int)f2bf(a1 * inv) << 16);
    ((unsigned int*)(mean + (size_t)v * C))[lane] = o;
  } else {
    const uint2* fp = (const uint2*)feat;  // 64 uint2/row
    float a0 = 0.f, a1 = 0.f, a2 = 0.f, a3 = 0.f;
    if (deg <= 64) {
      int idx = (lane < deg) ? esrc[s0 + lane] : 0;
      int e = 0;
      for (; e + 4 <= deg; e += 4) {
        int i0 = __shfl(idx, e), i1 = __shfl(idx, e + 1), i2 = __shfl(idx, e + 2), i3 = __shfl(idx, e + 3);
        uint2 u0 = fp[(size_t)i0 * 64 + lane];
        uint2 u1 = fp[(size_t)i1 * 64 + lane];
        uint2 u2 = fp[(size_t)i2 * 64 + lane];
        uint2 u3 = fp[(size_t)i3 * 64 + lane];
        a0 += bf2f(u0.x & 0xffffu); a1 += bf2f(u0.x >> 16); a2 += bf2f(u0.y & 0xffffu); a3 += bf2f(u0.y >> 16);
        a0 += bf2f(u1.x & 0xffffu); a1 += bf2f(u1.x >> 16); a2 += bf2f(u1.y & 0xffffu); a3 += bf2f(u1.y >> 16);
        a0 += bf2f(u2.x & 0xffffu); a1 += bf2f(u2.x >> 16); a2 += bf2f(u2.y & 0xffffu); a3 += bf2f(u2.y >> 16);
        a0 += bf2f(u3.x & 0xffffu); a1 += bf2f(u3.x >> 16); a2 += bf2f(u3.y & 0xffffu); a3 += bf2f(u3.y >> 16);
      }
      for (; e < deg; e++) {
        int s = __shfl(idx, e);
        uint2 u = fp[(size_t)s * 64 + lane];
        a0 += bf2f(u.x & 0xffffu); a1 += bf2f(u.x >> 16); a2 += bf2f(u.y & 0xffffu); a3 += bf2f(u.y >> 16);
      }
    } else {
      for (int e = s0; e < s0 + deg; e++) {
        int s = esrc[e];
        uint2 u = fp[(size_t)s * 64 + lane];
        a0 += bf2f(u.x & 0xffffu); a1 += bf2f(u.x >> 16); a2 += bf2f(u.y & 0xffffu); a3 += bf2f(u.y >> 16);
      }
    }
    float inv = 1.0f / (float)(deg > 1 ? deg : 1);
    uint2 o;
    o.x = (unsigned int)f2bf(a0 * inv) | ((unsigned int)f2bf(a1 * inv) << 16);
    o.y = (unsigned int)f2bf(a2 * inv) | ((unsigned int)f2bf(a3 * inv) << 16);
    ((uint2*)(mean + (size_t)v * C))[lane] = o;
  }
}

// ---------- dual-A bf16 MFMA GEMM: out = A1@W1 + A2@W2 + b ----------
template <int BN>
__global__ __launch_bounds__(BN * 2) void k_gmm(
    const unsigned short* __restrict__ A1, const unsigned short* __restrict__ Wt1,
    const unsigned short* __restrict__ A2, const unsigned short* __restrict__ Wt2,
    const float* __restrict__ bias, int M, int K, int N,
    unsigned short* __restrict__ outB, float* __restrict__ outF, int relu) {
  constexpr int NWAVE = BN / 32;
  constexpr int ACHUNKS = 8;
  constexpr int BCHUNKS = BN / 16;
  __shared__ unsigned short As[128 * 32];
  __shared__ unsigned short Bs[BN * 32];
  const int t = threadIdx.x;
  const int w = t >> 6, lane = t & 63;
  const int quad = lane >> 4, l15 = lane & 15;
  const int wm = w & 1, wn = w >> 1;
  const int m0 = blockIdx.x * 128, n0 = blockIdx.y * BN;
  const int srow = lane >> 2, skc = (lane & 3) * 8;

  f32x4 acc[4][4];
  #pragma unroll
  for (int i = 0; i < 4; i++)
    #pragma unroll
    for (int j = 0; j < 4; j++) acc[i][j] = (f32x4){0.f, 0.f, 0.f, 0.f};

  #pragma unroll
  for (int ph = 0; ph < 2; ph++) {
    const unsigned short* A = ph ? A2 : A1;
    const unsigned short* Wt = ph ? Wt2 : Wt1;
    for (int k0 = 0; k0 < K; k0 += 32) {
      #pragma unroll
      for (int c = w; c < ACHUNKS; c += NWAVE) {
        int rg = m0 + c * 16 + srow;
        if (rg >= M) rg = M - 1;
        async_cp16(A + (size_t)rg * K + k0 + skc, As + c * 512);
      }
      #pragma unroll
      for (int c = w; c < BCHUNKS; c += NWAVE) {
        async_cp16(Wt + (size_t)(n0 + c * 16 + srow) * K + k0 + skc, Bs + c * 512);
      }
      __syncthreads();
      short8 af[4], bfr[4];
      #pragma unroll
      for (int mt = 0; mt < 4; mt++)
        af[mt] = *(const short8*)&As[(wm * 64 + mt * 16 + l15) * 32 + quad * 8];
      #pragma unroll
      for (int nt = 0; nt < 4; nt++)
        bfr[nt] = *(const short8*)&Bs[(wn * 64 + nt * 16 + l15) * 32 + quad * 8];
      #pragma unroll
      for (int mt = 0; mt < 4; mt++)
        #pragma unroll
        for (int nt = 0; nt < 4; nt++)
          acc[mt][nt] = __builtin_amdgcn_mfma_f32_16x16x32_bf16(af[mt], bfr[nt], acc[mt][nt], 0, 0, 0);
      __syncthreads();
    }
  }

  #pragma unroll
  for (int nt = 0; nt < 4; nt++) {
    int n = n0 + wn * 64 + nt * 16 + l15;
    float bia = bias[n];
    #pragma unroll
    for (int mt = 0; mt < 4; mt++) {
      #pragma unroll
      for (int r = 0; r < 4; r++) {
        int m = m0 + wm * 64 + mt * 16 + quad * 4 + r;
        if (m < M) {
          float v = acc[mt][nt][r] + bia;
          if (relu) v = fmaxf(v, 0.f);
          if (outB) outB[(size_t)m * N + n] = f2bf(v);
          else      outF[(size_t)m * N + n] = v;
        }
      }
    }
  }
}

// ---------- log_softmax over 64 cols, one wave per row ----------
__global__ __launch_bounds__(256) void k_lsm(float* __restrict__ out) {
  int row = blockIdx.x * 4 + (threadIdx.x >> 6);
  int lane = threadIdx.x & 63;
  float v = out[(size_t)row * 64 + lane];
  float m = v;
  #pragma unroll
  for (int s = 32; s; s >>= 1) m = fmaxf(m, __shfl_xor(m, s));
  float e = expf(v - m);
  float sum = e;
  #pragma unroll
  for (int s = 32; s; s >>= 1) sum += __shfl_xor(sum, s);
  out[(size_t)row * 64 + lane] = v - m - logf(sum);
}

extern "C" void kernel_launch(void* const* d_in, const int* in_sizes, int n_in,
                              void* d_out, int out_size, void* d_ws, size_t ws_size,
                              hipStream_t stream) {
  const float* x   = (const float*)d_in[0];
  const int*   ei  = (const int*)d_in[1];
  const float* W1l = (const float*)d_in[2];
  const float* W1r = (const float*)d_in[3];
  const float* b1  = (const float*)d_in[4];
  const float* W2l = (const float*)d_in[5];
  const float* W2r = (const float*)d_in[6];
  const float* b2  = (const float*)d_in[7];
  const float* W3l = (const float*)d_in[8];
  const float* W3r = (const float*)d_in[9];
  const float* b3  = (const float*)d_in[10];
  float* out = (float*)d_out;
  const int* src = ei;
  const int* dst = ei + NE;

  char* w = (char*)d_ws;
  auto alloc = [&](size_t bytes) {
    char* p = w;
    w += (bytes + 255) & ~(size_t)255;
    return p;
  };
  int* off  = (int*)alloc((NN + 1) * sizeof(int));
  int* cur  = (int*)alloc(NN * sizeof(int));
  int* part = (int*)alloc(256 * sizeof(int));
  int* esrc = (int*)alloc((size_t)NE * sizeof(int));
  unsigned short* xb = (unsigned short*)alloc((size_t)NN * 128 * 2);
  unsigned short* mb = (unsigned short*)alloc((size_t)NN * 256 * 2);
  unsigned short* h1 = (unsigned short*)alloc((size_t)NN * 256 * 2);
  unsigned short* h2 = (unsigned short*)alloc((size_t)NN * 128 * 2);
  unsigned short* t1l = (unsigned short*)alloc(128 * 256 * 2);
  unsigned short* t1r = (unsigned short*)alloc(128 * 256 * 2);
  unsigned short* t2l = (unsigned short*)alloc(256 * 128 * 2);
  unsigned short* t2r = (unsigned short*)alloc(256 * 128 * 2);
  unsigned short* t3l = (unsigned short*)alloc(128 * 64 * 2);
  unsigned short* t3r = (unsigned short*)alloc(128 * 64 * 2);

  const int NB = (NN + 1023) / 1024;  // 98 partials

  hipMemsetAsync(off, 0, (NN + 1) * sizeof(int), stream);
  k_count<<<(NE + 255) / 256, 256, 0, stream>>>(dst, off, NE);
  k_red<<<NB, 256, 0, stream>>>(off, part, NN);
  k_scan1<<<1, 256, 0, stream>>>(part, NB, off, NN);
  k_add<<<NB, 256, 0, stream>>>(off, cur, part, NN);
  k_fill<<<(NE + 255) / 256, 256, 0, stream>>>(src, dst, cur, esrc, NE);
  k_cast<<<((NN * 128 / 4) + 255) / 256, 256, 0, stream>>>(x, xb, NN * 128 / 4);
  // weight transposes (fp32 [K][N] -> bf16 [N][K])
  k_wt<<<(128 * 256 + 255) / 256, 256, 0, stream>>>(W1l, t1l, 128, 256);
  k_wt<<<(128 * 256 + 255) / 256, 256, 0, stream>>>(W1r, t1r, 128, 256);
  k_wt<<<(256 * 128 + 255) / 256, 256, 0, stream>>>(W2l, t2l, 256, 128);
  k_wt<<<(256 * 128 + 255) / 256, 256, 0, stream>>>(W2r, t2r, 256, 128);
  k_wt<<<(128 * 64 + 255) / 256, 256, 0, stream>>>(W3l, t3l, 128, 64);
  k_wt<<<(128 * 64 + 255) / 256, 256, 0, stream>>>(W3r, t3r, 128, 64);

  const int MB = (NN + 127) / 128;  // 782
  // layer 1: in=xb (C=128) -> h1 (C=256), relu
  k_gather<128><<<NN / 4, 256, 0, stream>>>(xb, off, esrc, mb);
  k_gmm<128><<<dim3(MB, 2), 256, 0, stream>>>(mb, t1l, xb, t1r, b1, NN, 128, 256, h1, nullptr, 1);
  // layer 2: in=h1 (C=256) -> h2 (C=128), relu
  k_gather<256><<<NN / 4, 256, 0, stream>>>(h1, off, esrc, mb);
  k_gmm<128><<<dim3(MB, 1), 256, 0, stream>>>(mb, t2l, h1, t2r, b2, NN, 256, 128, h2, nullptr, 1);
  // layer 3: in=h2 (C=128) -> out (C=64), no relu
  k_gather<128><<<NN / 4, 256, 0, stream>>>(h2, off, esrc, mb);
  k_gmm<64><<<dim3(MB, 1), 128, 0, stream>>>(mb, t3l, h2, t3r, b3, NN, 128, 64, nullptr, out, 0);
  // log_softmax in place
  k_lsm<<<NN / 4, 256, 0, stream>>>(out);
}

// Round 5
// 380.332 us; speedup vs baseline: 2.1423x; 1.2075x over previous
//
#include <hip/hip_runtime.h>

#define NN 100000
#define NE 600000

typedef __attribute__((ext_vector_type(8))) short short8;   // 8 bf16 (4 VGPRs)
typedef __attribute__((ext_vector_type(4))) float f32x4;    // MFMA C/D frag

static __device__ __forceinline__ float bf2f(unsigned int u16) {
  union { unsigned int i; float f; } v;
  v.i = u16 << 16;
  return v.f;
}
static __device__ __forceinline__ unsigned short f2bf(float f) {
  union { float f; unsigned int i; } v;
  v.f = f;
  unsigned int x = v.i;
  x += 0x7FFFu + ((x >> 16) & 1u);  // round-to-nearest-even
  return (unsigned short)(x >> 16);
}

static __device__ __forceinline__ void async_cp16(const unsigned short* g, unsigned short* l) {
  __builtin_amdgcn_global_load_lds(
      (const __attribute__((address_space(1))) unsigned int*)g,
      (__attribute__((address_space(3))) unsigned int*)l,
      16, 0, 0);
}

// ---------- CSR build ----------
__global__ void k_count(const int* __restrict__ dst, int* __restrict__ cnt, int E) {
  int i = blockIdx.x * blockDim.x + threadIdx.x;
  if (i < E) atomicAdd(&cnt[dst[i]], 1);
}

__global__ __launch_bounds__(256) void k_red(const int* __restrict__ off, int* __restrict__ part, int n) {
  __shared__ int ws[4];
  const int tid = threadIdx.x, wid = tid >> 6, lane = tid & 63;
  int i = blockIdx.x * 1024 + tid * 4;
  int s = 0;
  #pragma unroll
  for (int j = 0; j < 4; j++) if (i + j < n) s += off[i + j];
  #pragma unroll
  for (int d = 32; d; d >>= 1) s += __shfl_xor(s, d);
  if (lane == 0) ws[wid] = s;
  __syncthreads();
  if (tid == 0) part[blockIdx.x] = ws[0] + ws[1] + ws[2] + ws[3];
}

__global__ __launch_bounds__(256) void k_scan1(int* __restrict__ part, int nb, int* __restrict__ off, int n) {
  __shared__ int wsum[4];
  const int tid = threadIdx.x, wid = tid >> 6, lane = tid & 63;
  int v = (tid < nb) ? part[tid] : 0;
  int incl = v;
  #pragma unroll
  for (int d = 1; d < 64; d <<= 1) {
    int t = __shfl_up(incl, (unsigned)d);
    if (lane >= d) incl += t;
  }
  if (lane == 63) wsum[wid] = incl;
  __syncthreads();
  if (tid == 0) {
    int c = 0;
    #pragma unroll
    for (int w = 0; w < 4; w++) { int t = wsum[w]; wsum[w] = c; c += t; }
    off[n] = c;
  }
  __syncthreads();
  if (tid < nb) part[tid] = wsum[wid] + incl - v;
}

__global__ __launch_bounds__(256) void k_add(int* __restrict__ off, int* __restrict__ cur,
                                             const int* __restrict__ part, int n) {
  __shared__ int wsum[4];
  const int tid = threadIdx.x, wid = tid >> 6, lane = tid & 63;
  int i = blockIdx.x * 1024 + tid * 4;
  int v0 = (i + 0 < n) ? off[i + 0] : 0;
  int v1 = (i + 1 < n) ? off[i + 1] : 0;
  int v2 = (i + 2 < n) ? off[i + 2] : 0;
  int v3 = (i + 3 < n) ? off[i + 3] : 0;
  int s = v0 + v1 + v2 + v3;
  int incl = s;
  #pragma unroll
  for (int d = 1; d < 64; d <<= 1) {
    int t = __shfl_up(incl, (unsigned)d);
    if (lane >= d) incl += t;
  }
  if (lane == 63) wsum[wid] = incl;
  __syncthreads();
  if (tid == 0) {
    int c = 0;
    #pragma unroll
    for (int w = 0; w < 4; w++) { int t = wsum[w]; wsum[w] = c; c += t; }
  }
  __syncthreads();
  int excl = part[blockIdx.x] + wsum[wid] + (incl - s);
  if (i + 0 < n) { off[i + 0] = excl; cur[i + 0] = excl; } excl += v0;
  if (i + 1 < n) { off[i + 1] = excl; cur[i + 1] = excl; } excl += v1;
  if (i + 2 < n) { off[i + 2] = excl; cur[i + 2] = excl; } excl += v2;
  if (i + 3 < n) { off[i + 3] = excl; cur[i + 3] = excl; } excl += v3;
}

__global__ void k_fill(const int* __restrict__ src, const int* __restrict__ dst,
                       int* __restrict__ cur, int* __restrict__ esrc, int E) {
  int i = blockIdx.x * blockDim.x + threadIdx.x;
  if (i < E) {
    int p = atomicAdd(&cur[dst[i]], 1);
    esrc[p] = src[i];
  }
}

// ---------- fp32 -> bf16 cast (vectorized x4) ----------
__global__ void k_cast(const float* __restrict__ in, unsigned short* __restrict__ out, int n4) {
  int i = blockIdx.x * blockDim.x + threadIdx.x;
  if (i < n4) {
    float4 f = ((const float4*)in)[i];
    ushort4 o;
    o.x = f2bf(f.x); o.y = f2bf(f.y); o.z = f2bf(f.z); o.w = f2bf(f.w);
    ((ushort4*)out)[i] = o;
  }
}

// ---------- all 6 weight transposes in one launch: W[K][N] fp32 -> Wt[N][K] bf16 ----------
__global__ __launch_bounds__(256) void k_wt_all(
    const float* __restrict__ W0, const float* __restrict__ W1,
    const float* __restrict__ W2, const float* __restrict__ W3,
    const float* __restrict__ W4, const float* __restrict__ W5,
    unsigned short* __restrict__ T0, unsigned short* __restrict__ T1,
    unsigned short* __restrict__ T2, unsigned short* __restrict__ T3,
    unsigned short* __restrict__ T4, unsigned short* __restrict__ T5) {
  const float* W; unsigned short* T; int ks, N;
  switch (blockIdx.y) {
    case 0: W = W0; T = T0; ks = 7; N = 256; break;  // K=128
    case 1: W = W1; T = T1; ks = 7; N = 256; break;
    case 2: W = W2; T = T2; ks = 8; N = 128; break;  // K=256
    case 3: W = W3; T = T3; ks = 8; N = 128; break;
    case 4: W = W4; T = T4; ks = 7; N = 64;  break;
    default: W = W5; T = T5; ks = 7; N = 64; break;
  }
  int i = blockIdx.x * 256 + threadIdx.x;
  int K = 1 << ks;
  if (i < N * K) {
    int n = i >> ks, k = i & (K - 1);
    T[i] = f2bf(W[(size_t)k * N + n]);
  }
}

// ---------- CSR gather-mean (L1, C=128): 4 waves/block, one node/wave ----------
__global__ __launch_bounds__(256) void k_gather128(const unsigned short* __restrict__ feat,
                                                   const int* __restrict__ off,
                                                   const int* __restrict__ esrc,
                                                   unsigned short* __restrict__ mean) {
  const int v = blockIdx.x * 4 + (threadIdx.x >> 6);
  const int lane = threadIdx.x & 63;
  const int s0 = off[v], deg = off[v + 1] - s0;
  const unsigned int* fp = (const unsigned int*)feat;  // 64 uints/row
  float a0 = 0.f, a1 = 0.f;
  if (deg <= 64) {
    int idx = (lane < deg) ? esrc[s0 + lane] : 0;
    int e = 0;
    for (; e + 4 <= deg; e += 4) {
      int i0 = __shfl(idx, e), i1 = __shfl(idx, e + 1), i2 = __shfl(idx, e + 2), i3 = __shfl(idx, e + 3);
      unsigned int u0 = fp[(size_t)i0 * 64 + lane];
      unsigned int u1 = fp[(size_t)i1 * 64 + lane];
      unsigned int u2 = fp[(size_t)i2 * 64 + lane];
      unsigned int u3 = fp[(size_t)i3 * 64 + lane];
      a0 += bf2f(u0 & 0xffffu); a1 += bf2f(u0 >> 16);
      a0 += bf2f(u1 & 0xffffu); a1 += bf2f(u1 >> 16);
      a0 += bf2f(u2 & 0xffffu); a1 += bf2f(u2 >> 16);
      a0 += bf2f(u3 & 0xffffu); a1 += bf2f(u3 >> 16);
    }
    for (; e < deg; e++) {
      int s = __shfl(idx, e);
      unsigned int u = fp[(size_t)s * 64 + lane];
      a0 += bf2f(u & 0xffffu); a1 += bf2f(u >> 16);
    }
  } else {
    for (int e = s0; e < s0 + deg; e++) {
      int s = esrc[e];
      unsigned int u = fp[(size_t)s * 64 + lane];
      a0 += bf2f(u & 0xffffu); a1 += bf2f(u >> 16);
    }
  }
  float inv = 1.0f / (float)(deg > 1 ? deg : 1);
  unsigned int o = (unsigned int)f2bf(a0 * inv) | ((unsigned int)f2bf(a1 * inv) << 16);
  ((unsigned int*)(mean + (size_t)v * 128))[lane] = o;
}

// ---------- L2 fused: h2 = relu(mean(g[src]) + t), C=128 bf16 ----------
__global__ __launch_bounds__(256) void k_gather_add(const unsigned short* __restrict__ g,
                                                    const unsigned short* __restrict__ t,
                                                    const int* __restrict__ off,
                                                    const int* __restrict__ esrc,
                                                    unsigned short* __restrict__ outh) {
  const int v = blockIdx.x * 4 + (threadIdx.x >> 6);
  const int lane = threadIdx.x & 63;
  const int s0 = off[v], deg = off[v + 1] - s0;
  const unsigned int* fp = (const unsigned int*)g;
  float a0 = 0.f, a1 = 0.f;
  if (deg <= 64) {
    int idx = (lane < deg) ? esrc[s0 + lane] : 0;
    int e = 0;
    for (; e + 4 <= deg; e += 4) {
      int i0 = __shfl(idx, e), i1 = __shfl(idx, e + 1), i2 = __shfl(idx, e + 2), i3 = __shfl(idx, e + 3);
      unsigned int u0 = fp[(size_t)i0 * 64 + lane];
      unsigned int u1 = fp[(size_t)i1 * 64 + lane];
      unsigned int u2 = fp[(size_t)i2 * 64 + lane];
      unsigned int u3 = fp[(size_t)i3 * 64 + lane];
      a0 += bf2f(u0 & 0xffffu); a1 += bf2f(u0 >> 16);
      a0 += bf2f(u1 & 0xffffu); a1 += bf2f(u1 >> 16);
      a0 += bf2f(u2 & 0xffffu); a1 += bf2f(u2 >> 16);
      a0 += bf2f(u3 & 0xffffu); a1 += bf2f(u3 >> 16);
    }
    for (; e < deg; e++) {
      int s = __shfl(idx, e);
      unsigned int u = fp[(size_t)s * 64 + lane];
      a0 += bf2f(u & 0xffffu); a1 += bf2f(u >> 16);
    }
  } else {
    for (int e = s0; e < s0 + deg; e++) {
      int s = esrc[e];
      unsigned int u = fp[(size_t)s * 64 + lane];
      a0 += bf2f(u & 0xffffu); a1 += bf2f(u >> 16);
    }
  }
  float inv = 1.0f / (float)(deg > 1 ? deg : 1);
  unsigned int tu = ((const unsigned int*)t)[(size_t)v * 64 + lane];
  float r0 = fmaxf(a0 * inv + bf2f(tu & 0xffffu), 0.f);
  float r1 = fmaxf(a1 * inv + bf2f(tu >> 16), 0.f);
  unsigned int o = (unsigned int)f2bf(r0) | ((unsigned int)f2bf(r1) << 16);
  ((unsigned int*)(outh + (size_t)v * 128))[lane] = o;
}

// ---------- L3 fused: out = log_softmax(mean(g[src]) + t), C=64, fp32 out ----------
__global__ __launch_bounds__(256) void k_gather_lsm(const unsigned short* __restrict__ g,
                                                    const unsigned short* __restrict__ t,
                                                    const int* __restrict__ off,
                                                    const int* __restrict__ esrc,
                                                    float* __restrict__ out) {
  const int v = blockIdx.x * 4 + (threadIdx.x >> 6);
  const int lane = threadIdx.x & 63;
  const int s0 = off[v], deg = off[v + 1] - s0;
  float a = 0.f;
  if (deg <= 64) {
    int idx = (lane < deg) ? esrc[s0 + lane] : 0;
    int e = 0;
    for (; e + 4 <= deg; e += 4) {
      int i0 = __shfl(idx, e), i1 = __shfl(idx, e + 1), i2 = __shfl(idx, e + 2), i3 = __shfl(idx, e + 3);
      a += bf2f(g[(size_t)i0 * 64 + lane]);
      a += bf2f(g[(size_t)i1 * 64 + lane]);
      a += bf2f(g[(size_t)i2 * 64 + lane]);
      a += bf2f(g[(size_t)i3 * 64 + lane]);
    }
    for (; e < deg; e++) a += bf2f(g[(size_t)__shfl(idx, e) * 64 + lane]);
  } else {
    for (int e = s0; e < s0 + deg; e++) a += bf2f(g[(size_t)esrc[e] * 64 + lane]);
  }
  float inv = 1.0f / (float)(deg > 1 ? deg : 1);
  float val = a * inv + bf2f(t[(size_t)v * 64 + lane]);
  float m = val;
  #pragma unroll
  for (int s = 32; s; s >>= 1) m = fmaxf(m, __shfl_xor(m, s));
  float e = expf(val - m);
  float sum = e;
  #pragma unroll
  for (int s = 32; s; s >>= 1) sum += __shfl_xor(sum, s);
  out[(size_t)v * 64 + lane] = val - m - logf(sum);
}

// ---------- bf16 MFMA GEMM, LDS-repack coalesced epilogue ----------
// DUAL=true : out = A1@Wt1 + A2@Wt2 + bias (relu), N wide, n0 = blockIdx.y*BN.
// DUAL=false: blockIdx.y==0 -> out1 = A1@Wt1 (no bias); ==1 -> out2 = A1@Wt2 + bias. N==BN.
template <int BN, bool DUAL>
__global__ __launch_bounds__(BN * 2) void k_gmm(
    const unsigned short* __restrict__ A1, const unsigned short* __restrict__ Wt1,
    const unsigned short* __restrict__ A2, const unsigned short* __restrict__ Wt2,
    const float* __restrict__ bias, int M, int K, int N,
    unsigned short* __restrict__ out1, unsigned short* __restrict__ out2, int relu) {
  constexpr int NWAVE = BN / 32;
  constexpr int ACHUNKS = 8;
  constexpr int BCHUNKS = BN / 16;
  constexpr int STR = BN + 8;                       // repack slab row stride (ushort)
  __shared__ unsigned short smem[128 * 32 + BN * 32];
  unsigned short* As = smem;
  unsigned short* Bs = smem + 128 * 32;
  const int t = threadIdx.x;
  const int w = t >> 6, lane = t & 63;
  const int quad = lane >> 4, l15 = lane & 15;
  const int wm = w & 1, wn = w >> 1;                // BN=64: wn==0
  const int m0 = blockIdx.x * 128;
  const int n0 = DUAL ? blockIdx.y * BN : 0;
  const int srow = lane >> 2, skc = (lane & 3) * 8;

  const unsigned short* Wt = DUAL ? Wt1 : (blockIdx.y ? Wt2 : Wt1);
  unsigned short* out = DUAL ? out1 : (blockIdx.y ? out2 : out1);
  const float* bs = DUAL ? bias : (blockIdx.y ? bias : nullptr);

  f32x4 acc[4][4];
  #pragma unroll
  for (int i = 0; i < 4; i++)
    #pragma unroll
    for (int j = 0; j < 4; j++) acc[i][j] = (f32x4){0.f, 0.f, 0.f, 0.f};

  const int nph = DUAL ? 2 : 1;
  for (int ph = 0; ph < nph; ph++) {
    const unsigned short* A = (DUAL && ph) ? A2 : A1;
    const unsigned short* W = (DUAL && ph) ? Wt2 : Wt;
    for (int k0 = 0; k0 < K; k0 += 32) {
      #pragma unroll
      for (int c = w; c < ACHUNKS; c += NWAVE) {
        int rg = m0 + c * 16 + srow;
        if (rg >= M) rg = M - 1;
        async_cp16(A + (size_t)rg * K + k0 + skc, As + c * 512);
      }
      #pragma unroll
      for (int c = w; c < BCHUNKS; c += NWAVE) {
        async_cp16(W + (size_t)(n0 + c * 16 + srow) * K + k0 + skc, Bs + c * 512);
      }
      __syncthreads();
      short8 af[4], bfr[4];
      #pragma unroll
      for (int mt = 0; mt < 4; mt++)
        af[mt] = *(const short8*)&As[(wm * 64 + mt * 16 + l15) * 32 + quad * 8];
      #pragma unroll
      for (int nt = 0; nt < 4; nt++)
        bfr[nt] = *(const short8*)&Bs[(wn * 64 + nt * 16 + l15) * 32 + quad * 8];
      #pragma unroll
      for (int mt = 0; mt < 4; mt++)
        #pragma unroll
        for (int nt = 0; nt < 4; nt++)
          acc[mt][nt] = __builtin_amdgcn_mfma_f32_16x16x32_bf16(af[mt], bfr[nt], acc[mt][nt], 0, 0, 0);
      __syncthreads();
    }
  }

  // epilogue: repack per-mt slab (32 rows x BN cols bf16) in LDS -> 16B coalesced stores
  float bia[4];
  #pragma unroll
  for (int nt = 0; nt < 4; nt++)
    bia[nt] = bs ? bs[n0 + wn * 64 + nt * 16 + l15] : 0.f;
  constexpr int CH_PER_ROW = BN / 8;
  constexpr int TOT_CH = 32 * CH_PER_ROW;
  for (int mt = 0; mt < 4; mt++) {
    __syncthreads();
    #pragma unroll
    for (int nt = 0; nt < 4; nt++) {
      int col = wn * 64 + nt * 16 + l15;
      #pragma unroll
      for (int r = 0; r < 4; r++) {
        float v = acc[mt][nt][r] + bia[nt];
        if (relu) v = fmaxf(v, 0.f);
        smem[(wm * 16 + quad * 4 + r) * STR + col] = f2bf(v);
      }
    }
    __syncthreads();
    #pragma unroll
    for (int c = t; c < TOT_CH; c += BN * 2) {
      int row = c / CH_PER_ROW, ofs = (c % CH_PER_ROW) * 8;
      int m = m0 + (row >> 4) * 64 + mt * 16 + (row & 15);
      if (m < M)
        *(short8*)(out + (size_t)m * N + n0 + ofs) = *(const short8*)&smem[row * STR + ofs];
    }
  }
}

extern "C" void kernel_launch(void* const* d_in, const int* in_sizes, int n_in,
                              void* d_out, int out_size, void* d_ws, size_t ws_size,
                              hipStream_t stream) {
  const float* x   = (const float*)d_in[0];
  const int*   ei  = (const int*)d_in[1];
  const float* W1l = (const float*)d_in[2];
  const float* W1r = (const float*)d_in[3];
  const float* b1  = (const float*)d_in[4];
  const float* W2l = (const float*)d_in[5];
  const float* W2r = (const float*)d_in[6];
  const float* b2  = (const float*)d_in[7];
  const float* W3l = (const float*)d_in[8];
  const float* W3r = (const float*)d_in[9];
  const float* b3  = (const float*)d_in[10];
  float* out = (float*)d_out;
  const int* src = ei;
  const int* dst = ei + NE;

  char* w = (char*)d_ws;
  auto alloc = [&](size_t bytes) {
    char* p = w;
    w += (bytes + 255) & ~(size_t)255;
    return p;
  };
  int* off  = (int*)alloc((NN + 1) * sizeof(int));
  int* cur  = (int*)alloc(NN * sizeof(int));
  int* part = (int*)alloc(256 * sizeof(int));
  int* esrc = (int*)alloc((size_t)NE * sizeof(int));
  unsigned short* xb = (unsigned short*)alloc((size_t)NN * 128 * 2);
  unsigned short* mb = (unsigned short*)alloc((size_t)NN * 128 * 2);  // L1 mean; aliased as g2
  unsigned short* h1 = (unsigned short*)alloc((size_t)NN * 256 * 2);  // aliased as g3|t3 later
  unsigned short* h2 = (unsigned short*)alloc((size_t)NN * 128 * 2);
  unsigned short* t2 = (unsigned short*)alloc((size_t)NN * 128 * 2);
  unsigned short* t1l = (unsigned short*)alloc(128 * 256 * 2);
  unsigned short* t1r = (unsigned short*)alloc(128 * 256 * 2);
  unsigned short* t2l = (unsigned short*)alloc(256 * 128 * 2);
  unsigned short* t2r = (unsigned short*)alloc(256 * 128 * 2);
  unsigned short* t3l = (unsigned short*)alloc(128 * 64 * 2);
  unsigned short* t3r = (unsigned short*)alloc(128 * 64 * 2);
  unsigned short* g2 = mb;                       // reuse: mb dead after L1 GEMM
  unsigned short* g3 = h1;                       // reuse: h1 dead after L2 GEMM
  unsigned short* t3 = h1 + (size_t)NN * 64;

  const int NB = (NN + 1023) / 1024;  // 98

  hipMemsetAsync(off, 0, (NN + 1) * sizeof(int), stream);
  k_count<<<(NE + 255) / 256, 256, 0, stream>>>(dst, off, NE);
  k_red<<<NB, 256, 0, stream>>>(off, part, NN);
  k_scan1<<<1, 256, 0, stream>>>(part, NB, off, NN);
  k_add<<<NB, 256, 0, stream>>>(off, cur, part, NN);
  k_fill<<<(NE + 255) / 256, 256, 0, stream>>>(src, dst, cur, esrc, NE);
  k_cast<<<((NN * 128 / 4) + 255) / 256, 256, 0, stream>>>(x, xb, NN * 128 / 4);
  k_wt_all<<<dim3(128, 6), 256, 0, stream>>>(W1l, W1r, W2l, W2r, W3l, W3r,
                                             t1l, t1r, t2l, t2r, t3l, t3r);

  const int MB = (NN + 127) / 128;  // 782
  // L1: h1 = relu(mean(xb)@W1l + xb@W1r + b1)
  k_gather128<<<NN / 4, 256, 0, stream>>>(xb, off, esrc, mb);
  k_gmm<128, true><<<dim3(MB, 2), 256, 0, stream>>>(mb, t1l, xb, t1r, b1, NN, 128, 256, h1, nullptr, 1);
  // L2: g2 = h1@W2l ; t2 = h1@W2r + b2 ; h2 = relu(mean(g2[src]) + t2)
  k_gmm<128, false><<<dim3(MB, 2), 256, 0, stream>>>(h1, t2l, nullptr, t2r, b2, NN, 256, 128, g2, t2, 0);
  k_gather_add<<<NN / 4, 256, 0, stream>>>(g2, t2, off, esrc, h2);
  // L3: g3 = h2@W3l ; t3 = h2@W3r + b3 ; out = log_softmax(mean(g3[src]) + t3)
  k_gmm<64, false><<<dim3(MB, 2), 128, 0, stream>>>(h2, t3l, nullptr, t3r, b3, NN, 128, 64, g3, t3, 0);
  k_gather_lsm<<<NN / 4, 256, 0, stream>>>(g3, t3, off, esrc, out);
}

// Round 6
// 347.454 us; speedup vs baseline: 2.3450x; 1.0946x over previous
//
#include <hip/hip_runtime.h>

#define NN 100000
#define NE 600000

typedef __attribute__((ext_vector_type(8))) short short8;   // 8 bf16 (4 VGPRs)
typedef __attribute__((ext_vector_type(4))) float f32x4;    // MFMA C/D frag

static __device__ __forceinline__ float bf2f(unsigned int u16) {
  union { unsigned int i; float f; } v;
  v.i = u16 << 16;
  return v.f;
}
static __device__ __forceinline__ float bf2f_lo(unsigned int u) {  // low bf16 of packed uint
  union { unsigned int i; float f; } v;
  v.i = u << 16;
  return v.f;
}
static __device__ __forceinline__ float bf2f_hi(unsigned int u) {  // high bf16 of packed uint
  union { unsigned int i; float f; } v;
  v.i = u & 0xffff0000u;
  return v.f;
}
static __device__ __forceinline__ unsigned short f2bf(float f) {
  union { float f; unsigned int i; } v;
  v.f = f;
  unsigned int x = v.i;
  x += 0x7FFFu + ((x >> 16) & 1u);  // round-to-nearest-even
  return (unsigned short)(x >> 16);
}

static __device__ __forceinline__ void async_cp16(const unsigned short* g, unsigned short* l) {
  __builtin_amdgcn_global_load_lds(
      (const __attribute__((address_space(1))) unsigned int*)g,
      (__attribute__((address_space(3))) unsigned int*)l,
      16, 0, 0);
}

// ---------- CSR build ----------
__global__ void k_count(const int* __restrict__ dst, int* __restrict__ cnt, int E) {
  int i = blockIdx.x * blockDim.x + threadIdx.x;
  if (i < E) atomicAdd(&cnt[dst[i]], 1);
}

__global__ __launch_bounds__(256) void k_red(const int* __restrict__ off, int* __restrict__ part, int n) {
  __shared__ int ws[4];
  const int tid = threadIdx.x, wid = tid >> 6, lane = tid & 63;
  int i = blockIdx.x * 1024 + tid * 4;
  int s = 0;
  #pragma unroll
  for (int j = 0; j < 4; j++) if (i + j < n) s += off[i + j];
  #pragma unroll
  for (int d = 32; d; d >>= 1) s += __shfl_xor(s, d);
  if (lane == 0) ws[wid] = s;
  __syncthreads();
  if (tid == 0) part[blockIdx.x] = ws[0] + ws[1] + ws[2] + ws[3];
}

__global__ __launch_bounds__(256) void k_scan1(int* __restrict__ part, int nb, int* __restrict__ off, int n) {
  __shared__ int wsum[4];
  const int tid = threadIdx.x, wid = tid >> 6, lane = tid & 63;
  int v = (tid < nb) ? part[tid] : 0;
  int incl = v;
  #pragma unroll
  for (int d = 1; d < 64; d <<= 1) {
    int t = __shfl_up(incl, (unsigned)d);
    if (lane >= d) incl += t;
  }
  if (lane == 63) wsum[wid] = incl;
  __syncthreads();
  if (tid == 0) {
    int c = 0;
    #pragma unroll
    for (int w = 0; w < 4; w++) { int t = wsum[w]; wsum[w] = c; c += t; }
    off[n] = c;
  }
  __syncthreads();
  if (tid < nb) part[tid] = wsum[wid] + incl - v;
}

__global__ __launch_bounds__(256) void k_add(int* __restrict__ off, int* __restrict__ cur,
                                             const int* __restrict__ part, int n) {
  __shared__ int wsum[4];
  const int tid = threadIdx.x, wid = tid >> 6, lane = tid & 63;
  int i = blockIdx.x * 1024 + tid * 4;
  int v0 = (i + 0 < n) ? off[i + 0] : 0;
  int v1 = (i + 1 < n) ? off[i + 1] : 0;
  int v2 = (i + 2 < n) ? off[i + 2] : 0;
  int v3 = (i + 3 < n) ? off[i + 3] : 0;
  int s = v0 + v1 + v2 + v3;
  int incl = s;
  #pragma unroll
  for (int d = 1; d < 64; d <<= 1) {
    int t = __shfl_up(incl, (unsigned)d);
    if (lane >= d) incl += t;
  }
  if (lane == 63) wsum[wid] = incl;
  __syncthreads();
  if (tid == 0) {
    int c = 0;
    #pragma unroll
    for (int w = 0; w < 4; w++) { int t = wsum[w]; wsum[w] = c; c += t; }
  }
  __syncthreads();
  int excl = part[blockIdx.x] + wsum[wid] + (incl - s);
  if (i + 0 < n) { off[i + 0] = excl; cur[i + 0] = excl; } excl += v0;
  if (i + 1 < n) { off[i + 1] = excl; cur[i + 1] = excl; } excl += v1;
  if (i + 2 < n) { off[i + 2] = excl; cur[i + 2] = excl; } excl += v2;
  if (i + 3 < n) { off[i + 3] = excl; cur[i + 3] = excl; } excl += v3;
}

__global__ void k_fill(const int* __restrict__ src, const int* __restrict__ dst,
                       int* __restrict__ cur, int* __restrict__ esrc, int E) {
  int i = blockIdx.x * blockDim.x + threadIdx.x;
  if (i < E) {
    int p = atomicAdd(&cur[dst[i]], 1);
    esrc[p] = src[i];
  }
}

// ---------- fp32 -> bf16 cast (vectorized x4) ----------
__global__ void k_cast(const float* __restrict__ in, unsigned short* __restrict__ out, int n4) {
  int i = blockIdx.x * blockDim.x + threadIdx.x;
  if (i < n4) {
    float4 f = ((const float4*)in)[i];
    ushort4 o;
    o.x = f2bf(f.x); o.y = f2bf(f.y); o.z = f2bf(f.z); o.w = f2bf(f.w);
    ((ushort4*)out)[i] = o;
  }
}

// ---------- all 6 weight transposes in one launch: W[K][N] fp32 -> Wt[N][K] bf16 ----------
__global__ __launch_bounds__(256) void k_wt_all(
    const float* __restrict__ W0, const float* __restrict__ W1,
    const float* __restrict__ W2, const float* __restrict__ W3,
    const float* __restrict__ W4, const float* __restrict__ W5,
    unsigned short* __restrict__ T0, unsigned short* __restrict__ T1,
    unsigned short* __restrict__ T2, unsigned short* __restrict__ T3,
    unsigned short* __restrict__ T4, unsigned short* __restrict__ T5) {
  const float* W; unsigned short* T; int ks, N;
  switch (blockIdx.y) {
    case 0: W = W0; T = T0; ks = 7; N = 256; break;  // K=128
    case 1: W = W1; T = T1; ks = 7; N = 256; break;
    case 2: W = W2; T = T2; ks = 8; N = 128; break;  // K=256
    case 3: W = W3; T = T3; ks = 8; N = 128; break;
    case 4: W = W4; T = T4; ks = 7; N = 64;  break;
    default: W = W5; T = T5; ks = 7; N = 64; break;
  }
  int i = blockIdx.x * 256 + threadIdx.x;
  int K = 1 << ks;
  if (i < N * K) {
    int n = i >> ks, k = i & (K - 1);
    T[i] = f2bf(W[(size_t)k * N + n]);
  }
}

// ---------- gather-mean, C=128 rows: 4 nodes/wave, 16 lanes/node, uint4 loads ----------
// ADD=false: out = mean(feat[src]) (bf16).  ADD=true: out = relu(mean(feat[src]) + t) (bf16).
template <bool ADD>
__global__ __launch_bounds__(256) void k_gather4_128(const unsigned short* __restrict__ feat,
                                                     const unsigned short* __restrict__ t,
                                                     const int* __restrict__ off,
                                                     const int* __restrict__ esrc,
                                                     unsigned short* __restrict__ outp) {
  const int tid = threadIdx.x;
  const int lane = tid & 63;
  const int sl = lane & 15;                         // sublane within 16-lane group
  const int v = blockIdx.x * 16 + (tid >> 4);       // 16 nodes per 256-thr block
  const int s0 = off[v], deg = off[v + 1] - s0;
  const int deg16 = deg < 16 ? deg : 16;
  int idx = (sl < deg16) ? esrc[s0 + sl] : 0;
  const uint4* fp = (const uint4*)feat;             // 16 uint4 per row

  float a0 = 0.f, a1 = 0.f, a2 = 0.f, a3 = 0.f, a4 = 0.f, a5 = 0.f, a6 = 0.f, a7 = 0.f;
  auto accum = [&](uint4 u) {
    a0 += bf2f_lo(u.x); a1 += bf2f_hi(u.x);
    a2 += bf2f_lo(u.y); a3 += bf2f_hi(u.y);
    a4 += bf2f_lo(u.z); a5 += bf2f_hi(u.z);
    a6 += bf2f_lo(u.w); a7 += bf2f_hi(u.w);
  };
  int e = 0;
  for (; e + 2 <= deg16; e += 2) {
    int i0 = __shfl(idx, e, 16);
    int i1 = __shfl(idx, e + 1, 16);
    uint4 u0 = fp[(size_t)i0 * 16 + sl];
    uint4 u1 = fp[(size_t)i1 * 16 + sl];
    accum(u0); accum(u1);
  }
  if (e < deg16) { accum(fp[(size_t)__shfl(idx, e, 16) * 16 + sl]); e++; }
  for (; e < deg; e++) accum(fp[(size_t)esrc[s0 + e] * 16 + sl]);  // rare deg>16 tail

  float inv = 1.0f / (float)(deg > 1 ? deg : 1);
  float r0, r1, r2, r3, r4, r5, r6, r7;
  if (ADD) {
    uint4 tu = ((const uint4*)t)[(size_t)v * 16 + sl];
    r0 = fmaxf(a0 * inv + bf2f_lo(tu.x), 0.f); r1 = fmaxf(a1 * inv + bf2f_hi(tu.x), 0.f);
    r2 = fmaxf(a2 * inv + bf2f_lo(tu.y), 0.f); r3 = fmaxf(a3 * inv + bf2f_hi(tu.y), 0.f);
    r4 = fmaxf(a4 * inv + bf2f_lo(tu.z), 0.f); r5 = fmaxf(a5 * inv + bf2f_hi(tu.z), 0.f);
    r6 = fmaxf(a6 * inv + bf2f_lo(tu.w), 0.f); r7 = fmaxf(a7 * inv + bf2f_hi(tu.w), 0.f);
  } else {
    r0 = a0 * inv; r1 = a1 * inv; r2 = a2 * inv; r3 = a3 * inv;
    r4 = a4 * inv; r5 = a5 * inv; r6 = a6 * inv; r7 = a7 * inv;
  }
  uint4 o;
  o.x = (unsigned int)f2bf(r0) | ((unsigned int)f2bf(r1) << 16);
  o.y = (unsigned int)f2bf(r2) | ((unsigned int)f2bf(r3) << 16);
  o.z = (unsigned int)f2bf(r4) | ((unsigned int)f2bf(r5) << 16);
  o.w = (unsigned int)f2bf(r6) | ((unsigned int)f2bf(r7) << 16);
  ((uint4*)outp)[(size_t)v * 16 + sl] = o;
}

// ---------- L3 fused: out = log_softmax(mean(g[src]) + t), C=64 rows, fp32 out ----------
// 4 nodes/wave, 16 lanes/node, uint2 loads; softmax reduced within 16-lane groups.
__global__ __launch_bounds__(256) void k_gather4_lsm(const unsigned short* __restrict__ g,
                                                     const unsigned short* __restrict__ t,
                                                     const int* __restrict__ off,
                                                     const int* __restrict__ esrc,
                                                     float* __restrict__ out) {
  const int tid = threadIdx.x;
  const int lane = tid & 63;
  const int sl = lane & 15;
  const int v = blockIdx.x * 16 + (tid >> 4);
  const int s0 = off[v], deg = off[v + 1] - s0;
  const int deg16 = deg < 16 ? deg : 16;
  int idx = (sl < deg16) ? esrc[s0 + sl] : 0;
  const uint2* fp = (const uint2*)g;                // 16 uint2 per row

  float a0 = 0.f, a1 = 0.f, a2 = 0.f, a3 = 0.f;
  auto accum = [&](uint2 u) {
    a0 += bf2f_lo(u.x); a1 += bf2f_hi(u.x);
    a2 += bf2f_lo(u.y); a3 += bf2f_hi(u.y);
  };
  int e = 0;
  for (; e + 2 <= deg16; e += 2) {
    int i0 = __shfl(idx, e, 16);
    int i1 = __shfl(idx, e + 1, 16);
    uint2 u0 = fp[(size_t)i0 * 16 + sl];
    uint2 u1 = fp[(size_t)i1 * 16 + sl];
    accum(u0); accum(u1);
  }
  if (e < deg16) { accum(fp[(size_t)__shfl(idx, e, 16) * 16 + sl]); e++; }
  for (; e < deg; e++) accum(fp[(size_t)esrc[s0 + e] * 16 + sl]);

  float inv = 1.0f / (float)(deg > 1 ? deg : 1);
  uint2 tu = ((const uint2*)t)[(size_t)v * 16 + sl];
  float v0 = a0 * inv + bf2f_lo(tu.x);
  float v1 = a1 * inv + bf2f_hi(tu.x);
  float v2 = a2 * inv + bf2f_lo(tu.y);
  float v3 = a3 * inv + bf2f_hi(tu.y);
  float m = fmaxf(fmaxf(v0, v1), fmaxf(v2, v3));
  #pragma unroll
  for (int s = 8; s; s >>= 1) m = fmaxf(m, __shfl_xor(m, s, 16));
  float sum = expf(v0 - m) + expf(v1 - m) + expf(v2 - m) + expf(v3 - m);
  #pragma unroll
  for (int s = 8; s; s >>= 1) sum += __shfl_xor(sum, s, 16);
  float ls = m + logf(sum);
  float4 o = make_float4(v0 - ls, v1 - ls, v2 - ls, v3 - ls);
  ((float4*)out)[(size_t)v * 16 + sl] = o;
}

// ---------- bf16 MFMA GEMM, LDS-repack coalesced epilogue ----------
// DUAL=true : out = A1@Wt1 + A2@Wt2 + bias (relu), N wide, n0 = blockIdx.y*BN.
// DUAL=false: blockIdx.y==0 -> out1 = A1@Wt1 (no bias); ==1 -> out2 = A1@Wt2 + bias. N==BN.
template <int BN, bool DUAL>
__global__ __launch_bounds__(BN * 2) void k_gmm(
    const unsigned short* __restrict__ A1, const unsigned short* __restrict__ Wt1,
    const unsigned short* __restrict__ A2, const unsigned short* __restrict__ Wt2,
    const float* __restrict__ bias, int M, int K, int N,
    unsigned short* __restrict__ out1, unsigned short* __restrict__ out2, int relu) {
  constexpr int NWAVE = BN / 32;
  constexpr int ACHUNKS = 8;
  constexpr int BCHUNKS = BN / 16;
  constexpr int STR = BN + 8;                       // repack slab row stride (ushort)
  __shared__ unsigned short smem[128 * 32 + BN * 32];
  unsigned short* As = smem;
  unsigned short* Bs = smem + 128 * 32;
  const int t = threadIdx.x;
  const int w = t >> 6, lane = t & 63;
  const int quad = lane >> 4, l15 = lane & 15;
  const int wm = w & 1, wn = w >> 1;                // BN=64: wn==0
  const int m0 = blockIdx.x * 128;
  const int n0 = DUAL ? blockIdx.y * BN : 0;
  const int srow = lane >> 2, skc = (lane & 3) * 8;

  const unsigned short* Wt = DUAL ? Wt1 : (blockIdx.y ? Wt2 : Wt1);
  unsigned short* out = DUAL ? out1 : (blockIdx.y ? out2 : out1);
  const float* bs = DUAL ? bias : (blockIdx.y ? bias : nullptr);

  f32x4 acc[4][4];
  #pragma unroll
  for (int i = 0; i < 4; i++)
    #pragma unroll
    for (int j = 0; j < 4; j++) acc[i][j] = (f32x4){0.f, 0.f, 0.f, 0.f};

  const int nph = DUAL ? 2 : 1;
  for (int ph = 0; ph < nph; ph++) {
    const unsigned short* A = (DUAL && ph) ? A2 : A1;
    const unsigned short* W = (DUAL && ph) ? Wt2 : Wt;
    for (int k0 = 0; k0 < K; k0 += 32) {
      #pragma unroll
      for (int c = w; c < ACHUNKS; c += NWAVE) {
        int rg = m0 + c * 16 + srow;
        if (rg >= M) rg = M - 1;
        async_cp16(A + (size_t)rg * K + k0 + skc, As + c * 512);
      }
      #pragma unroll
      for (int c = w; c < BCHUNKS; c += NWAVE) {
        async_cp16(W + (size_t)(n0 + c * 16 + srow) * K + k0 + skc, Bs + c * 512);
      }
      __syncthreads();
      short8 af[4], bfr[4];
      #pragma unroll
      for (int mt = 0; mt < 4; mt++)
        af[mt] = *(const short8*)&As[(wm * 64 + mt * 16 + l15) * 32 + quad * 8];
      #pragma unroll
      for (int nt = 0; nt < 4; nt++)
        bfr[nt] = *(const short8*)&Bs[(wn * 64 + nt * 16 + l15) * 32 + quad * 8];
      #pragma unroll
      for (int mt = 0; mt < 4; mt++)
        #pragma unroll
        for (int nt = 0; nt < 4; nt++)
          acc[mt][nt] = __builtin_amdgcn_mfma_f32_16x16x32_bf16(af[mt], bfr[nt], acc[mt][nt], 0, 0, 0);
      __syncthreads();
    }
  }

  // epilogue: repack per-mt slab (32 rows x BN cols bf16) in LDS -> 16B coalesced stores
  float bia[4];
  #pragma unroll
  for (int nt = 0; nt < 4; nt++)
    bia[nt] = bs ? bs[n0 + wn * 64 + nt * 16 + l15] : 0.f;
  constexpr int CH_PER_ROW = BN / 8;
  constexpr int TOT_CH = 32 * CH_PER_ROW;
  for (int mt = 0; mt < 4; mt++) {
    __syncthreads();
    #pragma unroll
    for (int nt = 0; nt < 4; nt++) {
      int col = wn * 64 + nt * 16 + l15;
      #pragma unroll
      for (int r = 0; r < 4; r++) {
        float v = acc[mt][nt][r] + bia[nt];
        if (relu) v = fmaxf(v, 0.f);
        smem[(wm * 16 + quad * 4 + r) * STR + col] = f2bf(v);
      }
    }
    __syncthreads();
    #pragma unroll
    for (int c = t; c < TOT_CH; c += BN * 2) {
      int row = c / CH_PER_ROW, ofs = (c % CH_PER_ROW) * 8;
      int m = m0 + (row >> 4) * 64 + mt * 16 + (row & 15);
      if (m < M)
        *(short8*)(out + (size_t)m * N + n0 + ofs) = *(const short8*)&smem[row * STR + ofs];
    }
  }
}

extern "C" void kernel_launch(void* const* d_in, const int* in_sizes, int n_in,
                              void* d_out, int out_size, void* d_ws, size_t ws_size,
                              hipStream_t stream) {
  const float* x   = (const float*)d_in[0];
  const int*   ei  = (const int*)d_in[1];
  const float* W1l = (const float*)d_in[2];
  const float* W1r = (const float*)d_in[3];
  const float* b1  = (const float*)d_in[4];
  const float* W2l = (const float*)d_in[5];
  const float* W2r = (const float*)d_in[6];
  const float* b2  = (const float*)d_in[7];
  const float* W3l = (const float*)d_in[8];
  const float* W3r = (const float*)d_in[9];
  const float* b3  = (const float*)d_in[10];
  float* out = (float*)d_out;
  const int* src = ei;
  const int* dst = ei + NE;

  char* w = (char*)d_ws;
  auto alloc = [&](size_t bytes) {
    char* p = w;
    w += (bytes + 255) & ~(size_t)255;
    return p;
  };
  int* off  = (int*)alloc((NN + 1) * sizeof(int));
  int* cur  = (int*)alloc(NN * sizeof(int));
  int* part = (int*)alloc(256 * sizeof(int));
  int* esrc = (int*)alloc((size_t)NE * sizeof(int));
  unsigned short* xb = (unsigned short*)alloc((size_t)NN * 128 * 2);
  unsigned short* mb = (unsigned short*)alloc((size_t)NN * 128 * 2);  // L1 mean; aliased as g2
  unsigned short* h1 = (unsigned short*)alloc((size_t)NN * 256 * 2);  // aliased as g3|t3 later
  unsigned short* h2 = (unsigned short*)alloc((size_t)NN * 128 * 2);
  unsigned short* t2 = (unsigned short*)alloc((size_t)NN * 128 * 2);
  unsigned short* t1l = (unsigned short*)alloc(128 * 256 * 2);
  unsigned short* t1r = (unsigned short*)alloc(128 * 256 * 2);
  unsigned short* t2l = (unsigned short*)alloc(256 * 128 * 2);
  unsigned short* t2r = (unsigned short*)alloc(256 * 128 * 2);
  unsigned short* t3l = (unsigned short*)alloc(128 * 64 * 2);
  unsigned short* t3r = (unsigned short*)alloc(128 * 64 * 2);
  unsigned short* g2 = mb;                       // reuse: mb dead after L1 GEMM
  unsigned short* g3 = h1;                       // reuse: h1 dead after L2 GEMM
  unsigned short* t3 = h1 + (size_t)NN * 64;

  const int NB = (NN + 1023) / 1024;  // 98

  hipMemsetAsync(off, 0, (NN + 1) * sizeof(int), stream);
  k_count<<<(NE + 255) / 256, 256, 0, stream>>>(dst, off, NE);
  k_red<<<NB, 256, 0, stream>>>(off, part, NN);
  k_scan1<<<1, 256, 0, stream>>>(part, NB, off, NN);
  k_add<<<NB, 256, 0, stream>>>(off, cur, part, NN);
  k_fill<<<(NE + 255) / 256, 256, 0, stream>>>(src, dst, cur, esrc, NE);
  k_cast<<<((NN * 128 / 4) + 255) / 256, 256, 0, stream>>>(x, xb, NN * 128 / 4);
  k_wt_all<<<dim3(128, 6), 256, 0, stream>>>(W1l, W1r, W2l, W2r, W3l, W3r,
                                             t1l, t1r, t2l, t2r, t3l, t3r);

  const int MB = (NN + 127) / 128;  // 782
  const int GB = NN / 16;           // 6250 gather blocks (16 nodes/block)
  // L1: h1 = relu(mean(xb)@W1l + xb@W1r + b1)
  k_gather4_128<false><<<GB, 256, 0, stream>>>(xb, nullptr, off, esrc, mb);
  k_gmm<128, true><<<dim3(MB, 2), 256, 0, stream>>>(mb, t1l, xb, t1r, b1, NN, 128, 256, h1, nullptr, 1);
  // L2: g2 = h1@W2l ; t2 = h1@W2r + b2 ; h2 = relu(mean(g2[src]) + t2)
  k_gmm<128, false><<<dim3(MB, 2), 256, 0, stream>>>(h1, t2l, nullptr, t2r, b2, NN, 256, 128, g2, t2, 0);
  k_gather4_128<true><<<GB, 256, 0, stream>>>(g2, t2, off, esrc, h2);
  // L3: g3 = h2@W3l ; t3 = h2@W3r + b3 ; out = log_softmax(mean(g3[src]) + t3)
  k_gmm<64, false><<<dim3(MB, 2), 128, 0, stream>>>(h2, t3l, nullptr, t3r, b3, NN, 128, 64, g3, t3, 0);
  k_gather4_lsm<<<GB, 256, 0, stream>>>(g3, t3, off, esrc, out);
}

// Round 7
// 331.660 us; speedup vs baseline: 2.4567x; 1.0476x over previous
//
#include <hip/hip_runtime.h>

#define NN 100000
#define NE 600000

typedef __attribute__((ext_vector_type(8))) short short8;   // 8 bf16 (4 VGPRs)
typedef __attribute__((ext_vector_type(4))) float f32x4;    // MFMA C/D frag

static __device__ __forceinline__ float bf2f_lo(unsigned int u) {
  union { unsigned int i; float f; } v;
  v.i = u << 16;
  return v.f;
}
static __device__ __forceinline__ float bf2f_hi(unsigned int u) {
  union { unsigned int i; float f; } v;
  v.i = u & 0xffff0000u;
  return v.f;
}
static __device__ __forceinline__ unsigned short f2bf(float f) {
  union { float f; unsigned int i; } v;
  v.f = f;
  unsigned int x = v.i;
  x += 0x7FFFu + ((x >> 16) & 1u);  // round-to-nearest-even
  return (unsigned short)(x >> 16);
}

static __device__ __forceinline__ void async_cp16(const unsigned short* g, unsigned short* l) {
  __builtin_amdgcn_global_load_lds(
      (const __attribute__((address_space(1))) unsigned int*)g,
      (__attribute__((address_space(3))) unsigned int*)l,
      16, 0, 0);
}

// ---------- fused prologue: x cast (blocks 0..12499), weight transposes (..13075), deg count (..15419)
__global__ __launch_bounds__(256) void k_prep(
    const float* __restrict__ x, unsigned short* __restrict__ xb,
    const float* __restrict__ W1l, const float* __restrict__ W1r,
    const float* __restrict__ W2l, const float* __restrict__ W2r,
    const float* __restrict__ W3l, const float* __restrict__ W3r,
    unsigned short* __restrict__ t1l, unsigned short* __restrict__ t1r,
    unsigned short* __restrict__ t2l, unsigned short* __restrict__ t2r,
    unsigned short* __restrict__ t3l, unsigned short* __restrict__ t3r,
    const int* __restrict__ dst, int* __restrict__ cnt) {
  const int bid = blockIdx.x;
  if (bid < 12500) {                      // cast NN*128 fp32 -> bf16, float4-wide
    int i = bid * 256 + threadIdx.x;      // < 3,200,000
    float4 f = ((const float4*)x)[i];
    ushort4 o;
    o.x = f2bf(f.x); o.y = f2bf(f.y); o.z = f2bf(f.z); o.w = f2bf(f.w);
    ((ushort4*)xb)[i] = o;
  } else if (bid < 13076) {               // 6 weight transposes, 147456 elems
    int i = (bid - 12500) * 256 + threadIdx.x;
    const float* W; unsigned short* T; int ks, N;
    if (i < 65536)        { if (i < 32768) { W = W1l; T = t1l; } else { W = W1r; T = t1r; i -= 32768; } ks = 7; N = 256; }
    else if (i < 131072)  { if (i < 98304) { W = W2l; T = t2l; i -= 65536; } else { W = W2r; T = t2r; i -= 98304; } ks = 8; N = 128; }
    else                  { if (i < 139264) { W = W3l; T = t3l; i -= 131072; } else { W = W3r; T = t3r; i -= 139264; } ks = 7; N = 64; }
    int K = 1 << ks;
    int n = i >> ks, k = i & (K - 1);
    T[i] = f2bf(W[(size_t)k * N + n]);
  } else {                                // degree count
    int i = (bid - 13076) * 256 + threadIdx.x;
    if (i < NE) atomicAdd(&cnt[dst[i]], 1);
  }
}

// ---------- multi-block scan ----------
__global__ __launch_bounds__(256) void k_red(const int* __restrict__ off, int* __restrict__ part, int n) {
  __shared__ int ws[4];
  const int tid = threadIdx.x, wid = tid >> 6, lane = tid & 63;
  int i = blockIdx.x * 1024 + tid * 4;
  int s = 0;
  #pragma unroll
  for (int j = 0; j < 4; j++) if (i + j < n) s += off[i + j];
  #pragma unroll
  for (int d = 32; d; d >>= 1) s += __shfl_xor(s, d);
  if (lane == 0) ws[wid] = s;
  __syncthreads();
  if (tid == 0) part[blockIdx.x] = ws[0] + ws[1] + ws[2] + ws[3];
}

__global__ __launch_bounds__(256) void k_scan1(int* __restrict__ part, int nb, int* __restrict__ off, int n) {
  __shared__ int wsum[4];
  const int tid = threadIdx.x, wid = tid >> 6, lane = tid & 63;
  int v = (tid < nb) ? part[tid] : 0;
  int incl = v;
  #pragma unroll
  for (int d = 1; d < 64; d <<= 1) {
    int t = __shfl_up(incl, (unsigned)d);
    if (lane >= d) incl += t;
  }
  if (lane == 63) wsum[wid] = incl;
  __syncthreads();
  if (tid == 0) {
    int c = 0;
    #pragma unroll
    for (int w = 0; w < 4; w++) { int t = wsum[w]; wsum[w] = c; c += t; }
    off[n] = c;
  }
  __syncthreads();
  if (tid < nb) part[tid] = wsum[wid] + incl - v;
}

__global__ __launch_bounds__(256) void k_add(int* __restrict__ off, int* __restrict__ cur,
                                             const int* __restrict__ part, int n) {
  __shared__ int wsum[4];
  const int tid = threadIdx.x, wid = tid >> 6, lane = tid & 63;
  int i = blockIdx.x * 1024 + tid * 4;
  int v0 = (i + 0 < n) ? off[i + 0] : 0;
  int v1 = (i + 1 < n) ? off[i + 1] : 0;
  int v2 = (i + 2 < n) ? off[i + 2] : 0;
  int v3 = (i + 3 < n) ? off[i + 3] : 0;
  int s = v0 + v1 + v2 + v3;
  int incl = s;
  #pragma unroll
  for (int d = 1; d < 64; d <<= 1) {
    int t = __shfl_up(incl, (unsigned)d);
    if (lane >= d) incl += t;
  }
  if (lane == 63) wsum[wid] = incl;
  __syncthreads();
  if (tid == 0) {
    int c = 0;
    #pragma unroll
    for (int w = 0; w < 4; w++) { int t = wsum[w]; wsum[w] = c; c += t; }
  }
  __syncthreads();
  int excl = part[blockIdx.x] + wsum[wid] + (incl - s);
  if (i + 0 < n) { off[i + 0] = excl; cur[i + 0] = excl; } excl += v0;
  if (i + 1 < n) { off[i + 1] = excl; cur[i + 1] = excl; } excl += v1;
  if (i + 2 < n) { off[i + 2] = excl; cur[i + 2] = excl; } excl += v2;
  if (i + 3 < n) { off[i + 3] = excl; cur[i + 3] = excl; } excl += v3;
}

__global__ void k_fill(const int* __restrict__ src, const int* __restrict__ dst,
                       int* __restrict__ cur, int* __restrict__ esrc, int E) {
  int i = blockIdx.x * blockDim.x + threadIdx.x;
  if (i < E) {
    int p = atomicAdd(&cur[dst[i]], 1);
    esrc[p] = src[i];
  }
}

// ---------- gather-mean, C=128 rows: 4 nodes/wave, 16 lanes/node, uint4 loads, unroll-4 ----------
template <bool ADD>
__global__ __launch_bounds__(256) void k_gather4_128(const unsigned short* __restrict__ feat,
                                                     const unsigned short* __restrict__ t,
                                                     const int* __restrict__ off,
                                                     const int* __restrict__ esrc,
                                                     unsigned short* __restrict__ outp) {
  const int tid = threadIdx.x;
  const int sl = tid & 15;
  const int v = blockIdx.x * 16 + (tid >> 4);
  const int s0 = off[v], deg = off[v + 1] - s0;
  const int deg16 = deg < 16 ? deg : 16;
  int idx = (sl < deg16) ? esrc[s0 + sl] : 0;
  const uint4* fp = (const uint4*)feat;             // 16 uint4 per row

  float a0 = 0.f, a1 = 0.f, a2 = 0.f, a3 = 0.f, a4 = 0.f, a5 = 0.f, a6 = 0.f, a7 = 0.f;
  auto accum = [&](uint4 u) {
    a0 += bf2f_lo(u.x); a1 += bf2f_hi(u.x);
    a2 += bf2f_lo(u.y); a3 += bf2f_hi(u.y);
    a4 += bf2f_lo(u.z); a5 += bf2f_hi(u.z);
    a6 += bf2f_lo(u.w); a7 += bf2f_hi(u.w);
  };
  int e = 0;
  for (; e + 4 <= deg16; e += 4) {
    int i0 = __shfl(idx, e, 16), i1 = __shfl(idx, e + 1, 16);
    int i2 = __shfl(idx, e + 2, 16), i3 = __shfl(idx, e + 3, 16);
    uint4 u0 = fp[(size_t)i0 * 16 + sl];
    uint4 u1 = fp[(size_t)i1 * 16 + sl];
    uint4 u2 = fp[(size_t)i2 * 16 + sl];
    uint4 u3 = fp[(size_t)i3 * 16 + sl];
    accum(u0); accum(u1); accum(u2); accum(u3);
  }
  for (; e < deg16; e++) accum(fp[(size_t)__shfl(idx, e, 16) * 16 + sl]);
  for (; e < deg; e++) accum(fp[(size_t)esrc[s0 + e] * 16 + sl]);  // rare deg>16 tail

  float inv = 1.0f / (float)(deg > 1 ? deg : 1);
  float r0, r1, r2, r3, r4, r5, r6, r7;
  if (ADD) {
    uint4 tu = ((const uint4*)t)[(size_t)v * 16 + sl];
    r0 = fmaxf(a0 * inv + bf2f_lo(tu.x), 0.f); r1 = fmaxf(a1 * inv + bf2f_hi(tu.x), 0.f);
    r2 = fmaxf(a2 * inv + bf2f_lo(tu.y), 0.f); r3 = fmaxf(a3 * inv + bf2f_hi(tu.y), 0.f);
    r4 = fmaxf(a4 * inv + bf2f_lo(tu.z), 0.f); r5 = fmaxf(a5 * inv + bf2f_hi(tu.z), 0.f);
    r6 = fmaxf(a6 * inv + bf2f_lo(tu.w), 0.f); r7 = fmaxf(a7 * inv + bf2f_hi(tu.w), 0.f);
  } else {
    r0 = a0 * inv; r1 = a1 * inv; r2 = a2 * inv; r3 = a3 * inv;
    r4 = a4 * inv; r5 = a5 * inv; r6 = a6 * inv; r7 = a7 * inv;
  }
  uint4 o;
  o.x = (unsigned int)f2bf(r0) | ((unsigned int)f2bf(r1) << 16);
  o.y = (unsigned int)f2bf(r2) | ((unsigned int)f2bf(r3) << 16);
  o.z = (unsigned int)f2bf(r4) | ((unsigned int)f2bf(r5) << 16);
  o.w = (unsigned int)f2bf(r6) | ((unsigned int)f2bf(r7) << 16);
  ((uint4*)outp)[(size_t)v * 16 + sl] = o;
}

// ---------- L3 fused: out = log_softmax(mean(g[src]) + t), C=64 rows ----------
// 8 nodes/wave, 8 lanes/node, uint4 (16B) loads; softmax within 8-lane groups.
__global__ __launch_bounds__(256) void k_gather8_lsm(const unsigned short* __restrict__ g,
                                                     const unsigned short* __restrict__ t,
                                                     const int* __restrict__ off,
                                                     const int* __restrict__ esrc,
                                                     float* __restrict__ out) {
  const int tid = threadIdx.x;
  const int sl = tid & 7;
  const int v = blockIdx.x * 32 + (tid >> 3);
  const int s0 = off[v], deg = off[v + 1] - s0;
  const int deg8 = deg < 8 ? deg : 8;
  const int deg16 = deg < 16 ? deg : 16;
  int idxA = (sl < deg8) ? esrc[s0 + sl] : 0;
  int idxB = (sl + 8 < deg16) ? esrc[s0 + 8 + sl] : 0;
  const uint4* fp = (const uint4*)g;                // 8 uint4 per row

  float a0 = 0.f, a1 = 0.f, a2 = 0.f, a3 = 0.f, a4 = 0.f, a5 = 0.f, a6 = 0.f, a7 = 0.f;
  auto accum = [&](uint4 u) {
    a0 += bf2f_lo(u.x); a1 += bf2f_hi(u.x);
    a2 += bf2f_lo(u.y); a3 += bf2f_hi(u.y);
    a4 += bf2f_lo(u.z); a5 += bf2f_hi(u.z);
    a6 += bf2f_lo(u.w); a7 += bf2f_hi(u.w);
  };
  int e = 0;
  for (; e + 4 <= deg8; e += 4) {
    int i0 = __shfl(idxA, e, 8), i1 = __shfl(idxA, e + 1, 8);
    int i2 = __shfl(idxA, e + 2, 8), i3 = __shfl(idxA, e + 3, 8);
    uint4 u0 = fp[(size_t)i0 * 8 + sl];
    uint4 u1 = fp[(size_t)i1 * 8 + sl];
    uint4 u2 = fp[(size_t)i2 * 8 + sl];
    uint4 u3 = fp[(size_t)i3 * 8 + sl];
    accum(u0); accum(u1); accum(u2); accum(u3);
  }
  for (; e < deg8; e++) accum(fp[(size_t)__shfl(idxA, e, 8) * 8 + sl]);
  for (; e < deg16; e++) accum(fp[(size_t)__shfl(idxB, e - 8, 8) * 8 + sl]);
  for (; e < deg; e++) accum(fp[(size_t)esrc[s0 + e] * 8 + sl]);

  float inv = 1.0f / (float)(deg > 1 ? deg : 1);
  uint4 tu = ((const uint4*)t)[(size_t)v * 8 + sl];
  float v0 = a0 * inv + bf2f_lo(tu.x), v1 = a1 * inv + bf2f_hi(tu.x);
  float v2 = a2 * inv + bf2f_lo(tu.y), v3 = a3 * inv + bf2f_hi(tu.y);
  float v4 = a4 * inv + bf2f_lo(tu.z), v5 = a5 * inv + bf2f_hi(tu.z);
  float v6 = a6 * inv + bf2f_lo(tu.w), v7 = a7 * inv + bf2f_hi(tu.w);
  float m = fmaxf(fmaxf(fmaxf(v0, v1), fmaxf(v2, v3)), fmaxf(fmaxf(v4, v5), fmaxf(v6, v7)));
  #pragma unroll
  for (int s = 4; s; s >>= 1) m = fmaxf(m, __shfl_xor(m, s, 8));
  float sum = expf(v0 - m) + expf(v1 - m) + expf(v2 - m) + expf(v3 - m)
            + expf(v4 - m) + expf(v5 - m) + expf(v6 - m) + expf(v7 - m);
  #pragma unroll
  for (int s = 4; s; s >>= 1) sum += __shfl_xor(sum, s, 8);
  float ls = m + logf(sum);
  float4* op = (float4*)out;
  op[(size_t)v * 16 + sl * 2 + 0] = make_float4(v0 - ls, v1 - ls, v2 - ls, v3 - ls);
  op[(size_t)v * 16 + sl * 2 + 1] = make_float4(v4 - ls, v5 - ls, v6 - ls, v7 - ls);
}

// ---------- bf16 MFMA GEMM, BK=64, XOR-swizzled LDS, coalesced repack epilogue ----------
// DUAL=true : out = A1@Wt1 + A2@Wt2 + bias (relu), n0 = blockIdx.y*BN.
// DUAL=false: blockIdx.y==0 -> out1 = A1@Wt1 (no bias); ==1 -> out2 = A1@Wt2 + bias. N==BN.
// LDS layout: row-major [row][64], but 16B chunk p of row r holds global k-chunk p^(r&7).
template <int BN, bool DUAL>
__global__ __launch_bounds__(BN * 2) void k_gmm(
    const unsigned short* __restrict__ A1, const unsigned short* __restrict__ Wt1,
    const unsigned short* __restrict__ A2, const unsigned short* __restrict__ Wt2,
    const float* __restrict__ bias, int M, int K, int N,
    unsigned short* __restrict__ out1, unsigned short* __restrict__ out2, int relu) {
  constexpr int NWAVE = BN / 32;          // 4 or 2
  constexpr int ACHUNKS = 16;             // 128 rows / 8 rows-per-chunk
  constexpr int BCHUNKS = BN / 8;
  constexpr int STR = BN + 8;             // repack slab row stride
  __shared__ unsigned short smem[128 * 64 + BN * 64];
  unsigned short* As = smem;
  unsigned short* Bs = smem + 128 * 64;
  const int t = threadIdx.x;
  const int w = t >> 6, lane = t & 63;
  const int quad = lane >> 4, l15 = lane & 15;
  const int wm = w & 1, wn = w >> 1;      // BN=64: wn==0
  const int m0 = blockIdx.x * 128;
  const int n0 = DUAL ? blockIdx.y * BN : 0;
  const int srow = lane >> 3;             // row in 8-row chunk
  const int sk = (((lane & 7) ^ (srow & 7)) * 8);  // swizzled source k-offset (elems)

  const unsigned short* Wt = DUAL ? Wt1 : (blockIdx.y ? Wt2 : Wt1);
  unsigned short* out = DUAL ? out1 : (blockIdx.y ? out2 : out1);
  const float* bs = DUAL ? bias : (blockIdx.y ? bias : nullptr);

  f32x4 acc[4][4];
  #pragma unroll
  for (int i = 0; i < 4; i++)
    #pragma unroll
    for (int j = 0; j < 4; j++) acc[i][j] = (f32x4){0.f, 0.f, 0.f, 0.f};

  const int nph = DUAL ? 2 : 1;
  for (int ph = 0; ph < nph; ph++) {
    const unsigned short* A = (DUAL && ph) ? A2 : A1;
    const unsigned short* W = (DUAL && ph) ? Wt2 : Wt;
    for (int k0 = 0; k0 < K; k0 += 64) {
      #pragma unroll
      for (int c = w; c < ACHUNKS; c += NWAVE) {
        int rg = m0 + c * 8 + srow;
        if (rg >= M) rg = M - 1;          // clamp; epilogue guards stores
        async_cp16(A + (size_t)rg * K + k0 + sk, As + c * 512);
      }
      #pragma unroll
      for (int c = w; c < BCHUNKS; c += NWAVE) {
        async_cp16(W + (size_t)(n0 + c * 8 + srow) * K + k0 + sk, Bs + c * 512);
      }
      __syncthreads();
      short8 af[2][4], bfr[2][4];
      #pragma unroll
      for (int kh = 0; kh < 2; kh++) {
        #pragma unroll
        for (int mt = 0; mt < 4; mt++) {
          int r = wm * 64 + mt * 16 + l15;
          int cc = (kh * 4 + quad) ^ (r & 7);
          af[kh][mt] = *(const short8*)&As[r * 64 + cc * 8];
        }
        #pragma unroll
        for (int nt = 0; nt < 4; nt++) {
          int r = wn * 64 + nt * 16 + l15;
          int cc = (kh * 4 + quad) ^ (r & 7);
          bfr[kh][nt] = *(const short8*)&Bs[r * 64 + cc * 8];
        }
      }
      #pragma unroll
      for (int kh = 0; kh < 2; kh++)
        #pragma unroll
        for (int mt = 0; mt < 4; mt++)
          #pragma unroll
          for (int nt = 0; nt < 4; nt++)
            acc[mt][nt] = __builtin_amdgcn_mfma_f32_16x16x32_bf16(af[kh][mt], bfr[kh][nt], acc[mt][nt], 0, 0, 0);
      __syncthreads();
    }
  }

  // epilogue: repack per-mt slab (32 rows x BN cols bf16) in LDS -> 16B coalesced stores
  float bia[4];
  #pragma unroll
  for (int nt = 0; nt < 4; nt++)
    bia[nt] = bs ? bs[n0 + wn * 64 + nt * 16 + l15] : 0.f;
  constexpr int CH_PER_ROW = BN / 8;
  constexpr int TOT_CH = 32 * CH_PER_ROW;
  for (int mt = 0; mt < 4; mt++) {
    __syncthreads();
    #pragma unroll
    for (int nt = 0; nt < 4; nt++) {
      int col = wn * 64 + nt * 16 + l15;
      #pragma unroll
      for (int r = 0; r < 4; r++) {
        float v = acc[mt][nt][r] + bia[nt];
        if (relu) v = fmaxf(v, 0.f);
        smem[(wm * 16 + quad * 4 + r) * STR + col] = f2bf(v);
      }
    }
    __syncthreads();
    #pragma unroll
    for (int c = t; c < TOT_CH; c += BN * 2) {
      int row = c / CH_PER_ROW, ofs = (c % CH_PER_ROW) * 8;
      int m = m0 + (row >> 4) * 64 + mt * 16 + (row & 15);
      if (m < M)
        *(short8*)(out + (size_t)m * N + n0 + ofs) = *(const short8*)&smem[row * STR + ofs];
    }
  }
}

extern "C" void kernel_launch(void* const* d_in, const int* in_sizes, int n_in,
                              void* d_out, int out_size, void* d_ws, size_t ws_size,
                              hipStream_t stream) {
  const float* x   = (const float*)d_in[0];
  const int*   ei  = (const int*)d_in[1];
  const float* W1l = (const float*)d_in[2];
  const float* W1r = (const float*)d_in[3];
  const float* b1  = (const float*)d_in[4];
  const float* W2l = (const float*)d_in[5];
  const float* W2r = (const float*)d_in[6];
  const float* b2  = (const float*)d_in[7];
  const float* W3l = (const float*)d_in[8];
  const float* W3r = (const float*)d_in[9];
  const float* b3  = (const float*)d_in[10];
  float* out = (float*)d_out;
  const int* src = ei;
  const int* dst = ei + NE;

  char* w = (char*)d_ws;
  auto alloc = [&](size_t bytes) {
    char* p = w;
    w += (bytes + 255) & ~(size_t)255;
    return p;
  };
  int* off  = (int*)alloc((NN + 1) * sizeof(int));
  int* cur  = (int*)alloc(NN * sizeof(int));
  int* part = (int*)alloc(256 * sizeof(int));
  int* esrc = (int*)alloc((size_t)NE * sizeof(int));
  unsigned short* xb = (unsigned short*)alloc((size_t)NN * 128 * 2);
  unsigned short* mb = (unsigned short*)alloc((size_t)NN * 128 * 2);  // L1 mean; aliased as g2
  unsigned short* h1 = (unsigned short*)alloc((size_t)NN * 256 * 2);  // aliased as g3|t3 later
  unsigned short* h2 = (unsigned short*)alloc((size_t)NN * 128 * 2);
  unsigned short* t2 = (unsigned short*)alloc((size_t)NN * 128 * 2);
  unsigned short* t1l = (unsigned short*)alloc(128 * 256 * 2);
  unsigned short* t1r = (unsigned short*)alloc(128 * 256 * 2);
  unsigned short* t2l = (unsigned short*)alloc(256 * 128 * 2);
  unsigned short* t2r = (unsigned short*)alloc(256 * 128 * 2);
  unsigned short* t3l = (unsigned short*)alloc(128 * 64 * 2);
  unsigned short* t3r = (unsigned short*)alloc(128 * 64 * 2);
  unsigned short* g2 = mb;                       // reuse: mb dead after L1 GEMM
  unsigned short* g3 = h1;                       // reuse: h1 dead after L2 GEMM
  unsigned short* t3 = h1 + (size_t)NN * 64;

  const int NB = (NN + 1023) / 1024;  // 98

  hipMemsetAsync(off, 0, (NN + 1) * sizeof(int), stream);
  // fused cast + weight transpose + degree count
  k_prep<<<15420, 256, 0, stream>>>(x, xb, W1l, W1r, W2l, W2r, W3l, W3r,
                                    t1l, t1r, t2l, t2r, t3l, t3r, dst, off);
  k_red<<<NB, 256, 0, stream>>>(off, part, NN);
  k_scan1<<<1, 256, 0, stream>>>(part, NB, off, NN);
  k_add<<<NB, 256, 0, stream>>>(off, cur, part, NN);
  k_fill<<<(NE + 255) / 256, 256, 0, stream>>>(src, dst, cur, esrc, NE);

  const int MB = (NN + 127) / 128;  // 782
  const int GB16 = NN / 16;         // 6250
  const int GB32 = NN / 32;         // 3125
  // L1: h1 = relu(mean(xb)@W1l + xb@W1r + b1)
  k_gather4_128<false><<<GB16, 256, 0, stream>>>(xb, nullptr, off, esrc, mb);
  k_gmm<128, true><<<dim3(MB, 2), 256, 0, stream>>>(mb, t1l, xb, t1r, b1, NN, 128, 256, h1, nullptr, 1);
  // L2: g2 = h1@W2l ; t2 = h1@W2r + b2 ; h2 = relu(mean(g2[src]) + t2)
  k_gmm<128, false><<<dim3(MB, 2), 256, 0, stream>>>(h1, t2l, nullptr, t2r, b2, NN, 256, 128, g2, t2, 0);
  k_gather4_128<true><<<GB16, 256, 0, stream>>>(g2, t2, off, esrc, h2);
  // L3: g3 = h2@W3l ; t3 = h2@W3r + b3 ; out = log_softmax(mean(g3[src]) + t3)
  k_gmm<64, false><<<dim3(MB, 2), 128, 0, stream>>>(h2, t3l, nullptr, t3r, b3, NN, 128, 64, g3, t3, 0);
  k_gather8_lsm<<<GB32, 256, 0, stream>>>(g3, t3, off, esrc, out);
}